// Round 12
// baseline (226.890 us; speedup 1.0000x reference)
//
#include <hip/hip_runtime.h>
#include <hip/hip_bf16.h>
#include <math.h>

static constexpr int NN    = 100000;            // N_NODES
static constexpr int BSH   = 9;                 // bucket covers 512 nodes
static constexpr int NBUCK = (NN + 511) >> 9;   // 196
static constexpr int EPB   = 2048;              // edges per block in scatter (parallelism!)
static constexpr int CAP   = 24576;             // per-bucket region capacity (avg 16.3k)

typedef __attribute__((ext_vector_type(8))) short short8;
typedef __attribute__((ext_vector_type(4))) float f32x4;
typedef __attribute__((ext_vector_type(2))) float f32x2;

// HW fp8 conversion (gfx950). Word-select args must be IMMEDIATE constants.
#if defined(__has_builtin)
#  if __has_builtin(__builtin_amdgcn_cvt_pk_f32_fp8) && __has_builtin(__builtin_amdgcn_cvt_pk_fp8_f32)
#    define USE_HW_FP8 1
#  endif
#endif
#ifndef USE_HW_FP8
#  define USE_HW_FP8 0
#endif

__device__ __forceinline__ short f2bf(float f) {
    __hip_bfloat16 h = __float2bfloat16(f);
    return __builtin_bit_cast(short, h);
}

// ---- software fp8 e4m3 (fallback only) ----
__device__ __forceinline__ float fp8_dec_sw(unsigned b) {
    unsigned u = ((b & 0x80u) << 24) | ((b & 0x7Fu) << 20);
    return __builtin_bit_cast(float, u) * 0x1p120f;
}
__device__ __forceinline__ unsigned fp8_enc_sw(float f) {
    unsigned u = __builtin_bit_cast(unsigned, f * 0x1p-120f);
    unsigned s = (u >> 24) & 0x80u;
    unsigned mag = u & 0x7FFFFFFFu;
    unsigned t = mag + 0x7FFFFu + ((mag >> 20) & 1u);
    unsigned r = t >> 20;
    if (r > 0x7Eu) r = 0x7Eu;
    return s | r;
}

template<bool HI>
__device__ __forceinline__ f32x2 dec2w(unsigned u) {
#if USE_HW_FP8
    return __builtin_amdgcn_cvt_pk_f32_fp8(u, HI);
#else
    unsigned w = HI ? (u >> 16) : u;
    f32x2 r;
    r.x = fp8_dec_sw(w & 0xFFu);
    r.y = fp8_dec_sw((w >> 8) & 0xFFu);
    return r;
#endif
}
__device__ __forceinline__ unsigned enc2(float a, float b) {
#if USE_HW_FP8
    return (unsigned)__builtin_amdgcn_cvt_pk_fp8_f32(a, b, 0, false);
#else
    return fp8_enc_sw(a) | (fp8_enc_sw(b) << 8);
#endif
}

// accumulate 8 fp8 (uint2) into f32x2 a[4]
__device__ __forceinline__ void acc8(f32x2* a, uint2 u) {
    a[0] += dec2w<false>(u.x);
    a[1] += dec2w<true>(u.x);
    a[2] += dec2w<false>(u.y);
    a[3] += dec2w<true>(u.y);
}

// ---- edge index load ----
__device__ __forceinline__ long long ldidx(const void* __restrict__ p, long long i, int is64) {
    if (is64) return ((const long long* __restrict__)p)[i];
    return (long long)((const int* __restrict__)p)[i];
}

__global__ void k_detect(const unsigned int* __restrict__ e32, int* __restrict__ flag) {
    __shared__ int any_nz;
    if (threadIdx.x == 0) any_nz = 0;
    __syncthreads();
    unsigned int nz = 0;
    for (int w = 1 + 2 * (int)threadIdx.x; w < 4096; w += 512)
        nz |= e32[w];
    if (nz) atomicOr(&any_nz, 1);
    __syncthreads();
    if (threadIdx.x == 0) *flag = (any_nz == 0) ? 1 : 0;   // 1 => int64
}

// ---- one-pass bucketed edge scatter (high-occupancy: 1563 blocks) ----
__global__ void __launch_bounds__(256)
k_scatter_bucket(const void* __restrict__ eidx, const int* __restrict__ flag, long long E,
                 int* __restrict__ gcur, unsigned* __restrict__ ebuf) {
    __shared__ int h[NBUCK];   // hist -> block's base cursor per bucket
    for (int b = threadIdx.x; b < NBUCK; b += 256) h[b] = 0;
    __syncthreads();
    int is64 = *flag;
    long long base = (long long)blockIdx.x * EPB;
    long long end  = base + EPB < E ? base + EPB : E;
    // pass 1: histogram dst (slice is small -> second read below hits L1/L2)
    for (long long e = base + threadIdx.x; e < end; e += 256) {
        int d = (int)ldidx(eidx, E + e, is64);
        atomicAdd(&h[d >> BSH], 1);
    }
    __syncthreads();
    // reserve contiguous chunk in each bucket's region
    for (int b = threadIdx.x; b < NBUCK; b += 256)
        h[b] = atomicAdd(&gcur[b], h[b]);
    __syncthreads();
    // pass 2: scatter
    for (long long e = base + threadIdx.x; e < end; e += 256) {
        int s = (int)ldidx(eidx, e, is64);
        int d = (int)ldidx(eidx, E + e, is64);
        int bk = d >> BSH;
        int pos = atomicAdd(&h[bk], 1);
        ebuf[(long long)bk * CAP + pos] = (unsigned)s | ((unsigned)(d & 511) << 17);
    }
}

// exclusive scan of the 196 bucket counts -> global CSR bases; rowst[NN]=E
__global__ void k_bucket_starts(const int* __restrict__ gcnt, int* __restrict__ bstart,
                                int* __restrict__ rowst, int n) {
    if (threadIdx.x == 0) {
        int run = 0;
        for (int b = 0; b < NBUCK; ++b) { bstart[b] = run; run += gcnt[b]; }
        bstart[NBUCK] = run;
        rowst[n] = run;   // == E
    }
}

// per bucket (512 nodes), 1024 threads: counts + starts in LDS -> rowst, dinv, csr
__global__ void __launch_bounds__(1024)
k_bucket_csr(const unsigned* __restrict__ ebuf, const int* __restrict__ gcnt,
             const int* __restrict__ bstart, int* __restrict__ rowst,
             float* __restrict__ dinv, int* __restrict__ csr) {
    __shared__ int cnt[512];
    __shared__ int scn[512];
    __shared__ int cursor[512];
    int b = blockIdx.x;
    int t = threadIdx.x;
    int cb = gcnt[b];
    long long rbase = (long long)b * CAP;
    int bs = bstart[b];
    if (t < 512) cnt[t] = 0;
    __syncthreads();
    for (int i = t; i < cb; i += 1024) {
        unsigned ed = ebuf[rbase + i];
        atomicAdd(&cnt[ed >> 17], 1);
    }
    __syncthreads();
    if (t < 512) scn[t] = cnt[t];
    __syncthreads();
    for (int off = 1; off < 512; off <<= 1) {
        int v = 0;
        if (t < 512 && t >= off) v = scn[t - off];
        __syncthreads();
        if (t < 512) scn[t] += v;
        __syncthreads();
    }
    if (t < 512) {
        int start = bs + scn[t] - cnt[t];
        int gnode = (b << BSH) + t;
        if (gnode < NN) {
            rowst[gnode] = start;
            dinv[gnode]  = rsqrtf((float)(cnt[t] + 1));
        }
        cursor[t] = start;
    }
    __syncthreads();
    for (int i = t; i < cb; i += 1024) {
        unsigned ed = ebuf[rbase + i];
        int pos = atomicAdd(&cursor[ed >> 17], 1);
        csr[pos] = (int)(ed & 0x1FFFFu);
    }
}

// ---- MFMA GEMM machinery ----
template<int K, int NCOLS, int KT, int NT>
__global__ void k_packB(const float* __restrict__ W, short* __restrict__ P) {
    int t = blockIdx.x * blockDim.x + threadIdx.x;
    if (t >= KT * NT * 64) return;
    int kt = t / (NT * 64);
    int nt = (t / 64) % NT;
    int l  = t & 63;
    int g  = l >> 4;
#pragma unroll
    for (int e = 0; e < 8; ++e) {
        int k   = kt * 32 + g * 8 + e;
        int col = nt * 16 + (l & 15);
        float v = (col < NCOLS) ? W[k * NCOLS + col] : 0.0f;
        P[t * 8 + e] = f2bf(v);
    }
}

// H[i,:] = fp8( (X[i,:K] @ W) * dinv[i] ), fp32 accumulate via bf16 MFMA.
template<int K, int NCOLS, int KT, int NT, bool ABF16>
__global__ void __launch_bounds__(256)
k_mfma_gemm(const void* __restrict__ Xv, const short* __restrict__ packedB,
            const float* __restrict__ dinv, unsigned char* __restrict__ H, int n) {
    __shared__ alignas(16) short sW[KT * NT * 512];
    short8* dst = (short8*)sW;
    const short8* src = (const short8*)packedB;
    constexpr int TOT8 = KT * NT * 64;
    for (int i = threadIdx.x; i < TOT8; i += 256) dst[i] = src[i];
    __syncthreads();

    int wave = threadIdx.x >> 6, lane = threadIdx.x & 63;
    int g = lane >> 4;
    int arow = blockIdx.x * 64 + wave * 16 + (lane & 15);

    f32x4 acc[NT];
#pragma unroll
    for (int nt = 0; nt < NT; ++nt) acc[nt] = (f32x4){0.f, 0.f, 0.f, 0.f};

#pragma unroll
    for (int kt = 0; kt < KT; ++kt) {
        short8 a;
        if (arow < n) {
            int k0 = kt * 32 + g * 8;
            if (ABF16) {
                const short* xr = (const short*)Xv + (long long)arow * K;
                a = *(const short8*)(xr + k0);
            } else {
                const float* xr = (const float*)Xv + (long long)arow * K;
                float4 u = *(const float4*)(xr + k0);
                float4 v = *(const float4*)(xr + k0 + 4);
                a[0] = f2bf(u.x); a[1] = f2bf(u.y); a[2] = f2bf(u.z); a[3] = f2bf(u.w);
                a[4] = f2bf(v.x); a[5] = f2bf(v.y); a[6] = f2bf(v.z); a[7] = f2bf(v.w);
            }
        } else {
            a = (short8){0, 0, 0, 0, 0, 0, 0, 0};
        }
#pragma unroll
        for (int nt = 0; nt < NT; ++nt) {
            short8 bfr = dst[(kt * NT + nt) * 64 + lane];
            acc[nt] = __builtin_amdgcn_mfma_f32_16x16x32_bf16(a, bfr, acc[nt], 0, 0, 0);
        }
    }

    int c = lane & 15;
    int orow_base = blockIdx.x * 64 + wave * 16 + g * 4;
#pragma unroll
    for (int r = 0; r < 4; ++r) {
        int orow = orow_base + r;
        if (orow < n) {
            float di = dinv[orow];
            float v[NT];
#pragma unroll
            for (int nt = 0; nt < NT; ++nt) v[nt] = acc[nt][r] * di;
            unsigned char* hp = H + (long long)orow * NCOLS;
#pragma unroll
            for (int p = 0; p < NT; p += 2) {
                unsigned wrd = enc2(v[p], (p + 1 < NT) ? v[p + 1] : 0.0f);
                int col0 = p * 16 + c;
                if (col0 < NCOLS) hp[col0] = (unsigned char)(wrd & 0xFFu);
                if (p + 1 < NT) {
                    int col1 = col0 + 16;
                    if (col1 < NCOLS) hp[col1] = (unsigned char)((wrd >> 8) & 0xFFu);
                }
            }
        }
    }
}

// Layer-1 aggregate (F=64 fp8): ONE 8-LANE GROUP PER NODE (8 nodes/wave).
__global__ void __launch_bounds__(256)
k_gather_relu(const int* __restrict__ rowst, const int* __restrict__ csr,
              const unsigned char* __restrict__ h1s, const float* __restrict__ dinv,
              const float* __restrict__ b, unsigned short* __restrict__ out, int n) {
    long long gid = (long long)blockIdx.x * blockDim.x + threadIdx.x;
    int node = (int)(gid >> 3);
    int fe   = (int)(gid & 7);
    if (node >= n) return;          // group-uniform
    int jb = rowst[node], je = rowst[node + 1];
    unsigned feoff = (unsigned)fe << 3;

    f32x2 a0[4], a1[4];
#pragma unroll
    for (int q = 0; q < 4; ++q) { a0[q] = (f32x2){0.f, 0.f}; a1[q] = (f32x2){0.f, 0.f}; }

    int j = jb;
    for (; j + 1 < je; j += 2) {
        int s0 = csr[j];
        int s1 = csr[j + 1];
        uint2 u0 = *(const uint2*)(h1s + (((unsigned)s0 << 6) + feoff));
        uint2 u1 = *(const uint2*)(h1s + (((unsigned)s1 << 6) + feoff));
        acc8(a0, u0);
        acc8(a1, u1);
    }
    if (j < je) {
        int s0 = csr[j];
        uint2 u0 = *(const uint2*)(h1s + (((unsigned)s0 << 6) + feoff));
        acc8(a0, u0);
    }
#pragma unroll
    for (int q = 0; q < 4; ++q) a0[q] += a1[q];

    uint2 self = *(const uint2*)(h1s + (((unsigned)node << 6) + feoff));
    acc8(a0, self);
    float di = dinv[node];
    unsigned short r[8];
#pragma unroll
    for (int q = 0; q < 4; ++q) {
        float v0 = fmaxf(a0[q].x * di + b[8 * fe + 2 * q],     0.0f);
        float v1 = fmaxf(a0[q].y * di + b[8 * fe + 2 * q + 1], 0.0f);
        r[2 * q]     = (unsigned short)f2bf(v0);
        r[2 * q + 1] = (unsigned short)f2bf(v1);
    }
    uint4 pk;
    pk.x = (unsigned)r[0] | ((unsigned)r[1] << 16);
    pk.y = (unsigned)r[2] | ((unsigned)r[3] << 16);
    pk.z = (unsigned)r[4] | ((unsigned)r[5] << 16);
    pk.w = (unsigned)r[6] | ((unsigned)r[7] << 16);
    ((uint4*)(out + (long long)node * 64))[fe] = pk;
}

// Layer-2 aggregate + bias + log_softmax (F=40 fp8 in, fp32 out).
__global__ void __launch_bounds__(256)
k_gather_lsm(const int* __restrict__ rowst, const int* __restrict__ csr,
             const unsigned char* __restrict__ h2s, const float* __restrict__ dinv,
             const float* __restrict__ b, float* __restrict__ out, int n) {
    long long gid = (long long)blockIdx.x * blockDim.x + threadIdx.x;
    int node = (int)(gid >> 3);
    int fe   = (int)(gid & 7);
    if (node >= n) return;          // group-uniform
    bool act = (fe < 5);
    int jb = rowst[node], je = rowst[node + 1];
    unsigned feoff = (unsigned)fe << 3;

    f32x2 a0[4], a1[4];
#pragma unroll
    for (int q = 0; q < 4; ++q) { a0[q] = (f32x2){0.f, 0.f}; a1[q] = (f32x2){0.f, 0.f}; }

    int j = jb;
    for (; j + 1 < je; j += 2) {
        int s0 = csr[j];
        int s1 = csr[j + 1];
        if (act) {
            uint2 u0 = *(const uint2*)(h2s + ((unsigned)s0 * 40u + feoff));
            uint2 u1 = *(const uint2*)(h2s + ((unsigned)s1 * 40u + feoff));
            acc8(a0, u0);
            acc8(a1, u1);
        }
    }
    if (j < je && act) {
        int s0 = csr[j];
        uint2 u0 = *(const uint2*)(h2s + ((unsigned)s0 * 40u + feoff));
        acc8(a0, u0);
    }
#pragma unroll
    for (int q = 0; q < 4; ++q) a0[q] += a1[q];

    float va[8];
    float mloc = -INFINITY;
    if (act) {
        uint2 self = *(const uint2*)(h2s + ((unsigned)node * 40u + feoff));
        acc8(a0, self);
        float di = dinv[node];
#pragma unroll
        for (int q = 0; q < 4; ++q) {
            va[2 * q]     = a0[q].x * di + b[8 * fe + 2 * q];
            va[2 * q + 1] = a0[q].y * di + b[8 * fe + 2 * q + 1];
            mloc = fmaxf(mloc, fmaxf(va[2 * q], va[2 * q + 1]));
        }
    }
    float m = mloc;
    m = fmaxf(m, __shfl_xor(m, 1));
    m = fmaxf(m, __shfl_xor(m, 2));
    m = fmaxf(m, __shfl_xor(m, 4));
    float ex = 0.0f;
    if (act) {
#pragma unroll
        for (int k = 0; k < 8; ++k) ex += __expf(va[k] - m);
    }
    ex += __shfl_xor(ex, 1);
    ex += __shfl_xor(ex, 2);
    ex += __shfl_xor(ex, 4);
    float lse = __logf(ex);
    if (act) {
        float4 r0 = make_float4(va[0] - m - lse, va[1] - m - lse,
                                va[2] - m - lse, va[3] - m - lse);
        float4 r1 = make_float4(va[4] - m - lse, va[5] - m - lse,
                                va[6] - m - lse, va[7] - m - lse);
        *(float4*)(out + (long long)node * 40 + 8 * fe)     = r0;
        *(float4*)(out + (long long)node * 40 + 8 * fe + 4) = r1;
    }
}

extern "C" void kernel_launch(void* const* d_in, const int* in_sizes, int n_in,
                              void* d_out, int out_size, void* d_ws, size_t ws_size,
                              hipStream_t stream) {
    const float* x  = (const float*)d_in[0];
    const void*  ei = d_in[1];
    const float* W1 = (const float*)d_in[2];
    const float* b1 = (const float*)d_in[3];
    const float* W2 = (const float*)d_in[4];
    const float* b2 = (const float*)d_in[5];
    float* out = (float*)d_out;

    const long long E = (long long)in_sizes[1] / 2;   // 3,200,000
    const int nblk = (int)((E + EPB - 1) / EPB);      // 1563

    char* w = (char*)d_ws;
    auto alloc = [&](size_t bytes) -> void* {
        void* p = (void*)w;
        w += (bytes + 255) & ~(size_t)255;
        return p;
    };
    int*      flag    = (int*)     alloc(4);
    int*      gcur    = (int*)     alloc((size_t)NBUCK * 4);
    int*      bstart  = (int*)     alloc(((size_t)NBUCK + 1) * 4);
    int*      rowst   = (int*)     alloc(((size_t)NN + 1) * 4);
    float*    dinv    = (float*)   alloc((size_t)NN * 4);
    short*    pB1     = (short*)   alloc((size_t)8 * 4 * 64 * 8 * 2);   // 32 KB
    short*    pB2     = (short*)   alloc((size_t)2 * 3 * 64 * 8 * 2);   // 6 KB
    int*      csr     = (int*)     alloc((size_t)E * 4);
    unsigned* ebuf    = (unsigned*)alloc((size_t)NBUCK * CAP * 4);   // 19.3 MB
    unsigned short* agg1 = (unsigned short*)alloc((size_t)NN * 64 * 2);
    unsigned char* h1s = (unsigned char*)ebuf;   // ebuf dead before gemm1 writes h1s
    unsigned char* h2s = h1s;                    // h1s dead after k_gather_relu

    const int B = 256;
    auto cdiv = [](long long a, long long b) { return (int)((a + b - 1) / b); };

    // 0) dtype detection + weight packing
    k_detect<<<1, 256, 0, stream>>>((const unsigned int*)ei, flag);
    k_packB<256, 64, 8, 4><<<cdiv(8 * 4 * 64, B), B, 0, stream>>>(W1, pB1);
    k_packB<64, 40, 2, 3><<<cdiv(2 * 3 * 64, B), B, 0, stream>>>(W2, pB2);

    // 1) one-pass bucketed edge scatter + per-bucket CSR build (+ dinv)
    hipMemsetAsync(gcur, 0, (size_t)NBUCK * 4, stream);
    k_scatter_bucket<<<nblk, B, 0, stream>>>(ei, flag, E, gcur, ebuf);
    k_bucket_starts<<<1, 64, 0, stream>>>(gcur, bstart, rowst, NN);
    k_bucket_csr<<<NBUCK, 1024, 0, stream>>>(ebuf, gcur, bstart, rowst, dinv, csr);

    // 2) h1s = fp8( (x @ W1) * dinv[row] )   via bf16 MFMA
    k_mfma_gemm<256, 64, 8, 4, false><<<cdiv(NN, 64), B, 0, stream>>>(x, pB1, dinv, h1s, NN);

    // 3) layer-1 aggregate + bias + ReLU  (fp8 in -> bf16 out), 8 nodes/wave
    k_gather_relu<<<cdiv((long long)NN * 8, B), B, 0, stream>>>(rowst, csr, h1s, dinv, b1, agg1, NN);

    // 4) h2s = fp8( (agg1 @ W2) * dinv[row] )  via bf16 MFMA, bf16 A
    k_mfma_gemm<64, 40, 2, 3, true><<<cdiv(NN, 64), B, 0, stream>>>(agg1, pB2, dinv, h2s, NN);

    // 5) layer-2 aggregate + bias + log_softmax -> d_out (fp32), 8 nodes/wave
    k_gather_lsm<<<cdiv((long long)NN * 8, B), B, 0, stream>>>(rowst, csr, h2s, dinv, b2, out, NN);
}

// Round 13
// 203.216 us; speedup vs baseline: 1.1165x; 1.1165x over previous
//
#include <hip/hip_runtime.h>
#include <hip/hip_bf16.h>
#include <math.h>

static constexpr int NN    = 100000;            // N_NODES
static constexpr int BSH   = 9;                 // bucket covers 512 nodes
static constexpr int NBUCK = (NN + 511) >> 9;   // 196
static constexpr int EPB   = 8192;              // edges per block (391 blocks -> 77k reserve atomics)
static constexpr int SCT   = 1024;              // scatter_bucket threads (16 waves/block for latency hiding)
static constexpr int CAP   = 24576;             // per-bucket region capacity (avg 16.3k)

typedef __attribute__((ext_vector_type(8))) short short8;
typedef __attribute__((ext_vector_type(4))) float f32x4;
typedef __attribute__((ext_vector_type(2))) float f32x2;

// HW fp8 conversion (gfx950). Word-select args must be IMMEDIATE constants.
#if defined(__has_builtin)
#  if __has_builtin(__builtin_amdgcn_cvt_pk_f32_fp8) && __has_builtin(__builtin_amdgcn_cvt_pk_fp8_f32)
#    define USE_HW_FP8 1
#  endif
#endif
#ifndef USE_HW_FP8
#  define USE_HW_FP8 0
#endif

__device__ __forceinline__ short f2bf(float f) {
    __hip_bfloat16 h = __float2bfloat16(f);
    return __builtin_bit_cast(short, h);
}

// ---- software fp8 e4m3 (fallback only) ----
__device__ __forceinline__ float fp8_dec_sw(unsigned b) {
    unsigned u = ((b & 0x80u) << 24) | ((b & 0x7Fu) << 20);
    return __builtin_bit_cast(float, u) * 0x1p120f;
}
__device__ __forceinline__ unsigned fp8_enc_sw(float f) {
    unsigned u = __builtin_bit_cast(unsigned, f * 0x1p-120f);
    unsigned s = (u >> 24) & 0x80u;
    unsigned mag = u & 0x7FFFFFFFu;
    unsigned t = mag + 0x7FFFFu + ((mag >> 20) & 1u);
    unsigned r = t >> 20;
    if (r > 0x7Eu) r = 0x7Eu;
    return s | r;
}

template<bool HI>
__device__ __forceinline__ f32x2 dec2w(unsigned u) {
#if USE_HW_FP8
    return __builtin_amdgcn_cvt_pk_f32_fp8(u, HI);
#else
    unsigned w = HI ? (u >> 16) : u;
    f32x2 r;
    r.x = fp8_dec_sw(w & 0xFFu);
    r.y = fp8_dec_sw((w >> 8) & 0xFFu);
    return r;
#endif
}
__device__ __forceinline__ unsigned enc2(float a, float b) {
#if USE_HW_FP8
    return (unsigned)__builtin_amdgcn_cvt_pk_fp8_f32(a, b, 0, false);
#else
    return fp8_enc_sw(a) | (fp8_enc_sw(b) << 8);
#endif
}

// accumulate 8 fp8 (uint2) into f32x2 a[4]
__device__ __forceinline__ void acc8(f32x2* a, uint2 u) {
    a[0] += dec2w<false>(u.x);
    a[1] += dec2w<true>(u.x);
    a[2] += dec2w<false>(u.y);
    a[3] += dec2w<true>(u.y);
}

// ---- edge index load ----
__device__ __forceinline__ long long ldidx(const void* __restrict__ p, long long i, int is64) {
    if (is64) return ((const long long* __restrict__)p)[i];
    return (long long)((const int* __restrict__)p)[i];
}

__global__ void k_detect(const unsigned int* __restrict__ e32, int* __restrict__ flag) {
    __shared__ int any_nz;
    if (threadIdx.x == 0) any_nz = 0;
    __syncthreads();
    unsigned int nz = 0;
    for (int w = 1 + 2 * (int)threadIdx.x; w < 4096; w += 512)
        nz |= e32[w];
    if (nz) atomicOr(&any_nz, 1);
    __syncthreads();
    if (threadIdx.x == 0) *flag = (any_nz == 0) ? 1 : 0;   // 1 => int64
}

// ---- one-pass bucketed edge scatter ----
// 391 blocks x 16 waves: high occupancy WITHOUT raising the 77k reserve atomics.
__global__ void __launch_bounds__(SCT)
k_scatter_bucket(const void* __restrict__ eidx, const int* __restrict__ flag, long long E,
                 int* __restrict__ gcur, unsigned* __restrict__ ebuf) {
    __shared__ int h[NBUCK];   // hist -> block's base cursor per bucket
    for (int b = threadIdx.x; b < NBUCK; b += SCT) h[b] = 0;
    __syncthreads();
    int is64 = *flag;
    long long base = (long long)blockIdx.x * EPB;
    long long end  = base + EPB < E ? base + EPB : E;
    // pass 1: histogram dst (slice re-read below hits L1/L2)
    for (long long e = base + threadIdx.x; e < end; e += SCT) {
        int d = (int)ldidx(eidx, E + e, is64);
        atomicAdd(&h[d >> BSH], 1);
    }
    __syncthreads();
    // reserve contiguous chunk in each bucket's region (ONE atomic per block-bucket)
    for (int b = threadIdx.x; b < NBUCK; b += SCT)
        h[b] = atomicAdd(&gcur[b], h[b]);
    __syncthreads();
    // pass 2: scatter
    for (long long e = base + threadIdx.x; e < end; e += SCT) {
        int s = (int)ldidx(eidx, e, is64);
        int d = (int)ldidx(eidx, E + e, is64);
        int bk = d >> BSH;
        int pos = atomicAdd(&h[bk], 1);
        ebuf[(long long)bk * CAP + pos] = (unsigned)s | ((unsigned)(d & 511) << 17);
    }
}

// exclusive scan of the 196 bucket counts -> global CSR bases; rowst[NN]=E
__global__ void k_bucket_starts(const int* __restrict__ gcnt, int* __restrict__ bstart,
                                int* __restrict__ rowst, int n) {
    if (threadIdx.x == 0) {
        int run = 0;
        for (int b = 0; b < NBUCK; ++b) { bstart[b] = run; run += gcnt[b]; }
        bstart[NBUCK] = run;
        rowst[n] = run;   // == E
    }
}

// per bucket (512 nodes), 1024 threads: counts + starts in LDS -> rowst, dinv, csr
__global__ void __launch_bounds__(1024)
k_bucket_csr(const unsigned* __restrict__ ebuf, const int* __restrict__ gcnt,
             const int* __restrict__ bstart, int* __restrict__ rowst,
             float* __restrict__ dinv, int* __restrict__ csr) {
    __shared__ int cnt[512];
    __shared__ int scn[512];
    __shared__ int cursor[512];
    int b = blockIdx.x;
    int t = threadIdx.x;
    int cb = gcnt[b];
    long long rbase = (long long)b * CAP;
    int bs = bstart[b];
    if (t < 512) cnt[t] = 0;
    __syncthreads();
    for (int i = t; i < cb; i += 1024) {
        unsigned ed = ebuf[rbase + i];
        atomicAdd(&cnt[ed >> 17], 1);
    }
    __syncthreads();
    if (t < 512) scn[t] = cnt[t];
    __syncthreads();
    for (int off = 1; off < 512; off <<= 1) {
        int v = 0;
        if (t < 512 && t >= off) v = scn[t - off];
        __syncthreads();
        if (t < 512) scn[t] += v;
        __syncthreads();
    }
    if (t < 512) {
        int start = bs + scn[t] - cnt[t];
        int gnode = (b << BSH) + t;
        if (gnode < NN) {
            rowst[gnode] = start;
            dinv[gnode]  = rsqrtf((float)(cnt[t] + 1));
        }
        cursor[t] = start;
    }
    __syncthreads();
    for (int i = t; i < cb; i += 1024) {
        unsigned ed = ebuf[rbase + i];
        int pos = atomicAdd(&cursor[ed >> 17], 1);
        csr[pos] = (int)(ed & 0x1FFFFu);
    }
}

// ---- MFMA GEMM machinery ----
template<int K, int NCOLS, int KT, int NT>
__global__ void k_packB(const float* __restrict__ W, short* __restrict__ P) {
    int t = blockIdx.x * blockDim.x + threadIdx.x;
    if (t >= KT * NT * 64) return;
    int kt = t / (NT * 64);
    int nt = (t / 64) % NT;
    int l  = t & 63;
    int g  = l >> 4;
#pragma unroll
    for (int e = 0; e < 8; ++e) {
        int k   = kt * 32 + g * 8 + e;
        int col = nt * 16 + (l & 15);
        float v = (col < NCOLS) ? W[k * NCOLS + col] : 0.0f;
        P[t * 8 + e] = f2bf(v);
    }
}

// H[i,:] = fp8( (X[i,:K] @ W) * dinv[i] ), fp32 accumulate via bf16 MFMA.
template<int K, int NCOLS, int KT, int NT, bool ABF16>
__global__ void __launch_bounds__(256)
k_mfma_gemm(const void* __restrict__ Xv, const short* __restrict__ packedB,
            const float* __restrict__ dinv, unsigned char* __restrict__ H, int n) {
    __shared__ alignas(16) short sW[KT * NT * 512];
    short8* dst = (short8*)sW;
    const short8* src = (const short8*)packedB;
    constexpr int TOT8 = KT * NT * 64;
    for (int i = threadIdx.x; i < TOT8; i += 256) dst[i] = src[i];
    __syncthreads();

    int wave = threadIdx.x >> 6, lane = threadIdx.x & 63;
    int g = lane >> 4;
    int arow = blockIdx.x * 64 + wave * 16 + (lane & 15);

    f32x4 acc[NT];
#pragma unroll
    for (int nt = 0; nt < NT; ++nt) acc[nt] = (f32x4){0.f, 0.f, 0.f, 0.f};

#pragma unroll
    for (int kt = 0; kt < KT; ++kt) {
        short8 a;
        if (arow < n) {
            int k0 = kt * 32 + g * 8;
            if (ABF16) {
                const short* xr = (const short*)Xv + (long long)arow * K;
                a = *(const short8*)(xr + k0);
            } else {
                const float* xr = (const float*)Xv + (long long)arow * K;
                float4 u = *(const float4*)(xr + k0);
                float4 v = *(const float4*)(xr + k0 + 4);
                a[0] = f2bf(u.x); a[1] = f2bf(u.y); a[2] = f2bf(u.z); a[3] = f2bf(u.w);
                a[4] = f2bf(v.x); a[5] = f2bf(v.y); a[6] = f2bf(v.z); a[7] = f2bf(v.w);
            }
        } else {
            a = (short8){0, 0, 0, 0, 0, 0, 0, 0};
        }
#pragma unroll
        for (int nt = 0; nt < NT; ++nt) {
            short8 bfr = dst[(kt * NT + nt) * 64 + lane];
            acc[nt] = __builtin_amdgcn_mfma_f32_16x16x32_bf16(a, bfr, acc[nt], 0, 0, 0);
        }
    }

    int c = lane & 15;
    int orow_base = blockIdx.x * 64 + wave * 16 + g * 4;
#pragma unroll
    for (int r = 0; r < 4; ++r) {
        int orow = orow_base + r;
        if (orow < n) {
            float di = dinv[orow];
            float v[NT];
#pragma unroll
            for (int nt = 0; nt < NT; ++nt) v[nt] = acc[nt][r] * di;
            unsigned char* hp = H + (long long)orow * NCOLS;
#pragma unroll
            for (int p = 0; p < NT; p += 2) {
                unsigned wrd = enc2(v[p], (p + 1 < NT) ? v[p + 1] : 0.0f);
                int col0 = p * 16 + c;
                if (col0 < NCOLS) hp[col0] = (unsigned char)(wrd & 0xFFu);
                if (p + 1 < NT) {
                    int col1 = col0 + 16;
                    if (col1 < NCOLS) hp[col1] = (unsigned char)((wrd >> 8) & 0xFFu);
                }
            }
        }
    }
}

// Layer-1 aggregate (F=64 fp8): ONE 8-LANE GROUP PER NODE (8 nodes/wave).
__global__ void __launch_bounds__(256)
k_gather_relu(const int* __restrict__ rowst, const int* __restrict__ csr,
              const unsigned char* __restrict__ h1s, const float* __restrict__ dinv,
              const float* __restrict__ b, unsigned short* __restrict__ out, int n) {
    long long gid = (long long)blockIdx.x * blockDim.x + threadIdx.x;
    int node = (int)(gid >> 3);
    int fe   = (int)(gid & 7);
    if (node >= n) return;          // group-uniform
    int jb = rowst[node], je = rowst[node + 1];
    unsigned feoff = (unsigned)fe << 3;

    f32x2 a0[4], a1[4];
#pragma unroll
    for (int q = 0; q < 4; ++q) { a0[q] = (f32x2){0.f, 0.f}; a1[q] = (f32x2){0.f, 0.f}; }

    int j = jb;
    for (; j + 1 < je; j += 2) {
        int s0 = csr[j];
        int s1 = csr[j + 1];
        uint2 u0 = *(const uint2*)(h1s + (((unsigned)s0 << 6) + feoff));
        uint2 u1 = *(const uint2*)(h1s + (((unsigned)s1 << 6) + feoff));
        acc8(a0, u0);
        acc8(a1, u1);
    }
    if (j < je) {
        int s0 = csr[j];
        uint2 u0 = *(const uint2*)(h1s + (((unsigned)s0 << 6) + feoff));
        acc8(a0, u0);
    }
#pragma unroll
    for (int q = 0; q < 4; ++q) a0[q] += a1[q];

    uint2 self = *(const uint2*)(h1s + (((unsigned)node << 6) + feoff));
    acc8(a0, self);
    float di = dinv[node];
    unsigned short r[8];
#pragma unroll
    for (int q = 0; q < 4; ++q) {
        float v0 = fmaxf(a0[q].x * di + b[8 * fe + 2 * q],     0.0f);
        float v1 = fmaxf(a0[q].y * di + b[8 * fe + 2 * q + 1], 0.0f);
        r[2 * q]     = (unsigned short)f2bf(v0);
        r[2 * q + 1] = (unsigned short)f2bf(v1);
    }
    uint4 pk;
    pk.x = (unsigned)r[0] | ((unsigned)r[1] << 16);
    pk.y = (unsigned)r[2] | ((unsigned)r[3] << 16);
    pk.z = (unsigned)r[4] | ((unsigned)r[5] << 16);
    pk.w = (unsigned)r[6] | ((unsigned)r[7] << 16);
    ((uint4*)(out + (long long)node * 64))[fe] = pk;
}

// Layer-2 aggregate + bias + log_softmax (F=40 fp8 in, fp32 out).
__global__ void __launch_bounds__(256)
k_gather_lsm(const int* __restrict__ rowst, const int* __restrict__ csr,
             const unsigned char* __restrict__ h2s, const float* __restrict__ dinv,
             const float* __restrict__ b, float* __restrict__ out, int n) {
    long long gid = (long long)blockIdx.x * blockDim.x + threadIdx.x;
    int node = (int)(gid >> 3);
    int fe   = (int)(gid & 7);
    if (node >= n) return;          // group-uniform
    bool act = (fe < 5);
    int jb = rowst[node], je = rowst[node + 1];
    unsigned feoff = (unsigned)fe << 3;

    f32x2 a0[4], a1[4];
#pragma unroll
    for (int q = 0; q < 4; ++q) { a0[q] = (f32x2){0.f, 0.f}; a1[q] = (f32x2){0.f, 0.f}; }

    int j = jb;
    for (; j + 1 < je; j += 2) {
        int s0 = csr[j];
        int s1 = csr[j + 1];
        if (act) {
            uint2 u0 = *(const uint2*)(h2s + ((unsigned)s0 * 40u + feoff));
            uint2 u1 = *(const uint2*)(h2s + ((unsigned)s1 * 40u + feoff));
            acc8(a0, u0);
            acc8(a1, u1);
        }
    }
    if (j < je && act) {
        int s0 = csr[j];
        uint2 u0 = *(const uint2*)(h2s + ((unsigned)s0 * 40u + feoff));
        acc8(a0, u0);
    }
#pragma unroll
    for (int q = 0; q < 4; ++q) a0[q] += a1[q];

    float va[8];
    float mloc = -INFINITY;
    if (act) {
        uint2 self = *(const uint2*)(h2s + ((unsigned)node * 40u + feoff));
        acc8(a0, self);
        float di = dinv[node];
#pragma unroll
        for (int q = 0; q < 4; ++q) {
            va[2 * q]     = a0[q].x * di + b[8 * fe + 2 * q];
            va[2 * q + 1] = a0[q].y * di + b[8 * fe + 2 * q + 1];
            mloc = fmaxf(mloc, fmaxf(va[2 * q], va[2 * q + 1]));
        }
    }
    float m = mloc;
    m = fmaxf(m, __shfl_xor(m, 1));
    m = fmaxf(m, __shfl_xor(m, 2));
    m = fmaxf(m, __shfl_xor(m, 4));
    float ex = 0.0f;
    if (act) {
#pragma unroll
        for (int k = 0; k < 8; ++k) ex += __expf(va[k] - m);
    }
    ex += __shfl_xor(ex, 1);
    ex += __shfl_xor(ex, 2);
    ex += __shfl_xor(ex, 4);
    float lse = __logf(ex);
    if (act) {
        float4 r0 = make_float4(va[0] - m - lse, va[1] - m - lse,
                                va[2] - m - lse, va[3] - m - lse);
        float4 r1 = make_float4(va[4] - m - lse, va[5] - m - lse,
                                va[6] - m - lse, va[7] - m - lse);
        *(float4*)(out + (long long)node * 40 + 8 * fe)     = r0;
        *(float4*)(out + (long long)node * 40 + 8 * fe + 4) = r1;
    }
}

extern "C" void kernel_launch(void* const* d_in, const int* in_sizes, int n_in,
                              void* d_out, int out_size, void* d_ws, size_t ws_size,
                              hipStream_t stream) {
    const float* x  = (const float*)d_in[0];
    const void*  ei = d_in[1];
    const float* W1 = (const float*)d_in[2];
    const float* b1 = (const float*)d_in[3];
    const float* W2 = (const float*)d_in[4];
    const float* b2 = (const float*)d_in[5];
    float* out = (float*)d_out;

    const long long E = (long long)in_sizes[1] / 2;   // 3,200,000
    const int nblk = (int)((E + EPB - 1) / EPB);      // 391

    char* w = (char*)d_ws;
    auto alloc = [&](size_t bytes) -> void* {
        void* p = (void*)w;
        w += (bytes + 255) & ~(size_t)255;
        return p;
    };
    int*      flag    = (int*)     alloc(4);
    int*      gcur    = (int*)     alloc((size_t)NBUCK * 4);
    int*      bstart  = (int*)     alloc(((size_t)NBUCK + 1) * 4);
    int*      rowst   = (int*)     alloc(((size_t)NN + 1) * 4);
    float*    dinv    = (float*)   alloc((size_t)NN * 4);
    short*    pB1     = (short*)   alloc((size_t)8 * 4 * 64 * 8 * 2);   // 32 KB
    short*    pB2     = (short*)   alloc((size_t)2 * 3 * 64 * 8 * 2);   // 6 KB
    int*      csr     = (int*)     alloc((size_t)E * 4);
    unsigned* ebuf    = (unsigned*)alloc((size_t)NBUCK * CAP * 4);   // 19.3 MB
    unsigned short* agg1 = (unsigned short*)alloc((size_t)NN * 64 * 2);
    unsigned char* h1s = (unsigned char*)ebuf;   // ebuf dead before gemm1 writes h1s
    unsigned char* h2s = h1s;                    // h1s dead after k_gather_relu

    const int B = 256;
    auto cdiv = [](long long a, long long b) { return (int)((a + b - 1) / b); };

    // 0) dtype detection + weight packing
    k_detect<<<1, 256, 0, stream>>>((const unsigned int*)ei, flag);
    k_packB<256, 64, 8, 4><<<cdiv(8 * 4 * 64, B), B, 0, stream>>>(W1, pB1);
    k_packB<64, 40, 2, 3><<<cdiv(2 * 3 * 64, B), B, 0, stream>>>(W2, pB2);

    // 1) one-pass bucketed edge scatter + per-bucket CSR build (+ dinv)
    hipMemsetAsync(gcur, 0, (size_t)NBUCK * 4, stream);
    k_scatter_bucket<<<nblk, SCT, 0, stream>>>(ei, flag, E, gcur, ebuf);
    k_bucket_starts<<<1, 64, 0, stream>>>(gcur, bstart, rowst, NN);
    k_bucket_csr<<<NBUCK, 1024, 0, stream>>>(ebuf, gcur, bstart, rowst, dinv, csr);

    // 2) h1s = fp8( (x @ W1) * dinv[row] )   via bf16 MFMA
    k_mfma_gemm<256, 64, 8, 4, false><<<cdiv(NN, 64), B, 0, stream>>>(x, pB1, dinv, h1s, NN);

    // 3) layer-1 aggregate + bias + ReLU  (fp8 in -> bf16 out), 8 nodes/wave
    k_gather_relu<<<cdiv((long long)NN * 8, B), B, 0, stream>>>(rowst, csr, h1s, dinv, b1, agg1, NN);

    // 4) h2s = fp8( (agg1 @ W2) * dinv[row] )  via bf16 MFMA, bf16 A
    k_mfma_gemm<64, 40, 2, 3, true><<<cdiv(NN, 64), B, 0, stream>>>(agg1, pB2, dinv, h2s, NN);

    // 5) layer-2 aggregate + bias + log_softmax -> d_out (fp32), 8 nodes/wave
    k_gather_lsm<<<cdiv((long long)NN * 8, B), B, 0, stream>>>(rowst, csr, h2s, dinv, b2, out, NN);
}

// Round 14
// 193.385 us; speedup vs baseline: 1.1733x; 1.0508x over previous
//
#include <hip/hip_runtime.h>
#include <hip/hip_bf16.h>
#include <math.h>

static constexpr int NN    = 100000;            // N_NODES
static constexpr int BSH   = 9;                 // bucket covers 512 nodes
static constexpr int NBUCK = (NN + 511) >> 9;   // 196
static constexpr int EPB   = 8192;              // edges per block (391 blocks -> 77k reserve atomics)
static constexpr int SCT   = 1024;              // scatter threads (16 waves/block); 8 edges/thread
static constexpr int CAP   = 24576;             // per-bucket region capacity (avg 16.3k)

typedef __attribute__((ext_vector_type(8))) short short8;
typedef __attribute__((ext_vector_type(4))) float f32x4;
typedef __attribute__((ext_vector_type(2))) float f32x2;

// HW fp8 conversion (gfx950). Word-select args must be IMMEDIATE constants.
#if defined(__has_builtin)
#  if __has_builtin(__builtin_amdgcn_cvt_pk_f32_fp8) && __has_builtin(__builtin_amdgcn_cvt_pk_fp8_f32)
#    define USE_HW_FP8 1
#  endif
#endif
#ifndef USE_HW_FP8
#  define USE_HW_FP8 0
#endif

__device__ __forceinline__ short f2bf(float f) {
    __hip_bfloat16 h = __float2bfloat16(f);
    return __builtin_bit_cast(short, h);
}

// ---- software fp8 e4m3 (fallback only) ----
__device__ __forceinline__ float fp8_dec_sw(unsigned b) {
    unsigned u = ((b & 0x80u) << 24) | ((b & 0x7Fu) << 20);
    return __builtin_bit_cast(float, u) * 0x1p120f;
}
__device__ __forceinline__ unsigned fp8_enc_sw(float f) {
    unsigned u = __builtin_bit_cast(unsigned, f * 0x1p-120f);
    unsigned s = (u >> 24) & 0x80u;
    unsigned mag = u & 0x7FFFFFFFu;
    unsigned t = mag + 0x7FFFFu + ((mag >> 20) & 1u);
    unsigned r = t >> 20;
    if (r > 0x7Eu) r = 0x7Eu;
    return s | r;
}

template<bool HI>
__device__ __forceinline__ f32x2 dec2w(unsigned u) {
#if USE_HW_FP8
    return __builtin_amdgcn_cvt_pk_f32_fp8(u, HI);
#else
    unsigned w = HI ? (u >> 16) : u;
    f32x2 r;
    r.x = fp8_dec_sw(w & 0xFFu);
    r.y = fp8_dec_sw((w >> 8) & 0xFFu);
    return r;
#endif
}
__device__ __forceinline__ unsigned enc2(float a, float b) {
#if USE_HW_FP8
    return (unsigned)__builtin_amdgcn_cvt_pk_fp8_f32(a, b, 0, false);
#else
    return fp8_enc_sw(a) | (fp8_enc_sw(b) << 8);
#endif
}

// accumulate 8 fp8 (uint2) into f32x2 a[4]
__device__ __forceinline__ void acc8(f32x2* a, uint2 u) {
    a[0] += dec2w<false>(u.x);
    a[1] += dec2w<true>(u.x);
    a[2] += dec2w<false>(u.y);
    a[3] += dec2w<true>(u.y);
}

// ---- edge index load ----
__device__ __forceinline__ long long ldidx(const void* __restrict__ p, long long i, int is64) {
    if (is64) return ((const long long* __restrict__)p)[i];
    return (long long)((const int* __restrict__)p)[i];
}

// ---- weight pack (device helper) ----
// P[((kt*NT+nt)*64+lane)*8+e] = bf16(W[kt*32+(lane>>4)*8+e][nt*16+(lane&15)])
template<int K, int NCOLS, int KT, int NT>
__device__ __forceinline__ void packB_dev(const float* __restrict__ W,
                                          short* __restrict__ P, int t) {
    if (t >= KT * NT * 64) return;
    int kt = t / (NT * 64);
    int nt = (t / 64) % NT;
    int l  = t & 63;
    int g  = l >> 4;
#pragma unroll
    for (int e = 0; e < 8; ++e) {
        int k   = kt * 32 + g * 8 + e;
        int col = nt * 16 + (l & 15);
        float v = (col < NCOLS) ? W[k * NCOLS + col] : 0.0f;
        P[t * 8 + e] = f2bf(v);
    }
}

// Fused init: block 0 = dtype-detect + gcur zero; blocks 1-8 = packB1; 9-10 = packB2.
__global__ void __launch_bounds__(256)
k_init(const unsigned int* __restrict__ e32, int* __restrict__ flag,
       int* __restrict__ gcur,
       const float* __restrict__ W1, short* __restrict__ pB1,
       const float* __restrict__ W2, short* __restrict__ pB2) {
    int blk = blockIdx.x, tid = threadIdx.x;
    if (blk == 0) {
        if (tid < NBUCK) gcur[tid] = 0;
        __shared__ int any_nz;
        if (tid == 0) any_nz = 0;
        __syncthreads();
        unsigned int nz = 0;
        for (int w = 1 + 2 * tid; w < 4096; w += 512)
            nz |= e32[w];
        if (nz) atomicOr(&any_nz, 1);
        __syncthreads();
        if (tid == 0) *flag = (any_nz == 0) ? 1 : 0;   // 1 => int64
    } else if (blk <= 8) {
        packB_dev<256, 64, 8, 4>(W1, pB1, (blk - 1) * 256 + tid);
    } else {
        packB_dev<64, 40, 2, 3>(W2, pB2, (blk - 9) * 256 + tid);
    }
}

// ---- one-pass bucketed edge scatter (register-cached edges, single read) ----
__global__ void __launch_bounds__(SCT)
k_scatter_bucket(const void* __restrict__ eidx, const int* __restrict__ flag, long long E,
                 int* __restrict__ gcur, unsigned* __restrict__ ebuf) {
    __shared__ int h[NBUCK];   // hist -> block's base cursor per bucket
    for (int b = threadIdx.x; b < NBUCK; b += SCT) h[b] = 0;
    __syncthreads();
    int is64 = *flag;
    long long base = (long long)blockIdx.x * EPB;
    long long end  = base + EPB < E ? base + EPB : E;
    unsigned sv[8], dv[8];
    bool ok[8];
#pragma unroll
    for (int k = 0; k < 8; ++k) {
        long long e = base + (long long)k * SCT + threadIdx.x;
        ok[k] = (e < end);
        if (ok[k]) {
            sv[k] = (unsigned)ldidx(eidx, e, is64);
            dv[k] = (unsigned)ldidx(eidx, E + e, is64);
            atomicAdd(&h[dv[k] >> BSH], 1);
        }
    }
    __syncthreads();
    // reserve contiguous chunk per bucket (ONE global atomic per block-bucket)
    for (int b = threadIdx.x; b < NBUCK; b += SCT)
        h[b] = atomicAdd(&gcur[b], h[b]);
    __syncthreads();
#pragma unroll
    for (int k = 0; k < 8; ++k) {
        if (ok[k]) {
            int bk = dv[k] >> BSH;
            int pos = atomicAdd(&h[bk], 1);
            ebuf[(long long)bk * CAP + pos] = sv[k] | ((dv[k] & 511u) << 17);
        }
    }
}

// exclusive scan of the 196 bucket counts -> global CSR bases; rowst[NN]=E
__global__ void k_bucket_starts(const int* __restrict__ gcnt, int* __restrict__ bstart,
                                int* __restrict__ rowst, int n) {
    if (threadIdx.x == 0) {
        int run = 0;
        for (int b = 0; b < NBUCK; ++b) { bstart[b] = run; run += gcnt[b]; }
        bstart[NBUCK] = run;
        rowst[n] = run;   // == E
    }
}

// per bucket (512 nodes), 1024 threads: counts in LDS, wave-shuffle scan,
// emit rowst/dinv/csr.
__global__ void __launch_bounds__(1024)
k_bucket_csr(const unsigned* __restrict__ ebuf, const int* __restrict__ gcnt,
             const int* __restrict__ bstart, int* __restrict__ rowst,
             float* __restrict__ dinv, int* __restrict__ csr) {
    __shared__ int cnt[512];
    __shared__ int cursor[512];
    __shared__ int woff[8];
    int b = blockIdx.x;
    int t = threadIdx.x;
    int cb = gcnt[b];
    long long rbase = (long long)b * CAP;
    int bs = bstart[b];
    if (t < 512) cnt[t] = 0;
    __syncthreads();
    for (int i = t; i < cb; i += 1024) {
        unsigned ed = ebuf[rbase + i];
        atomicAdd(&cnt[ed >> 17], 1);
    }
    __syncthreads();
    int v = 0, ps = 0;
    if (t < 512) {
        v = cnt[t];
        ps = v;
        int lane = t & 63;
#pragma unroll
        for (int off = 1; off < 64; off <<= 1) {
            int up = __shfl_up(ps, off);
            if (lane >= off) ps += up;
        }
        if (lane == 63) woff[t >> 6] = ps;   // wave inclusive total
    }
    __syncthreads();
    if (t == 0) {
        int run = 0;
#pragma unroll
        for (int i = 0; i < 8; ++i) { int x = woff[i]; woff[i] = run; run += x; }
    }
    __syncthreads();
    if (t < 512) {
        int incl  = ps + woff[t >> 6];
        int start = bs + incl - v;           // exclusive
        int gnode = (b << BSH) + t;
        if (gnode < NN) {
            rowst[gnode] = start;
            dinv[gnode]  = rsqrtf((float)(v + 1));
        }
        cursor[t] = start;
    }
    __syncthreads();
    for (int i = t; i < cb; i += 1024) {
        unsigned ed = ebuf[rbase + i];
        int pos = atomicAdd(&cursor[ed >> 17], 1);
        csr[pos] = (int)(ed & 0x1FFFFu);
    }
}

// H[i,:] = fp8( (X[i,:K] @ W) * dinv[i] ), fp32 accumulate via bf16 MFMA.
template<int K, int NCOLS, int KT, int NT, bool ABF16>
__global__ void __launch_bounds__(256)
k_mfma_gemm(const void* __restrict__ Xv, const short* __restrict__ packedB,
            const float* __restrict__ dinv, unsigned char* __restrict__ H, int n) {
    __shared__ alignas(16) short sW[KT * NT * 512];
    short8* dst = (short8*)sW;
    const short8* src = (const short8*)packedB;
    constexpr int TOT8 = KT * NT * 64;
    for (int i = threadIdx.x; i < TOT8; i += 256) dst[i] = src[i];
    __syncthreads();

    int wave = threadIdx.x >> 6, lane = threadIdx.x & 63;
    int g = lane >> 4;
    int arow = blockIdx.x * 64 + wave * 16 + (lane & 15);

    f32x4 acc[NT];
#pragma unroll
    for (int nt = 0; nt < NT; ++nt) acc[nt] = (f32x4){0.f, 0.f, 0.f, 0.f};

#pragma unroll
    for (int kt = 0; kt < KT; ++kt) {
        short8 a;
        if (arow < n) {
            int k0 = kt * 32 + g * 8;
            if (ABF16) {
                const short* xr = (const short*)Xv + (long long)arow * K;
                a = *(const short8*)(xr + k0);
            } else {
                const float* xr = (const float*)Xv + (long long)arow * K;
                float4 u = *(const float4*)(xr + k0);
                float4 v = *(const float4*)(xr + k0 + 4);
                a[0] = f2bf(u.x); a[1] = f2bf(u.y); a[2] = f2bf(u.z); a[3] = f2bf(u.w);
                a[4] = f2bf(v.x); a[5] = f2bf(v.y); a[6] = f2bf(v.z); a[7] = f2bf(v.w);
            }
        } else {
            a = (short8){0, 0, 0, 0, 0, 0, 0, 0};
        }
#pragma unroll
        for (int nt = 0; nt < NT; ++nt) {
            short8 bfr = dst[(kt * NT + nt) * 64 + lane];
            acc[nt] = __builtin_amdgcn_mfma_f32_16x16x32_bf16(a, bfr, acc[nt], 0, 0, 0);
        }
    }

    // C/D layout (HW-verified): col = lane&15, row = (lane>>4)*4 + reg
    int c = lane & 15;
    int orow_base = blockIdx.x * 64 + wave * 16 + g * 4;
#pragma unroll
    for (int r = 0; r < 4; ++r) {
        int orow = orow_base + r;
        if (orow < n) {
            float di = dinv[orow];
            float v[NT];
#pragma unroll
            for (int nt = 0; nt < NT; ++nt) v[nt] = acc[nt][r] * di;
            unsigned char* hp = H + (long long)orow * NCOLS;
#pragma unroll
            for (int p = 0; p < NT; p += 2) {
                unsigned wrd = enc2(v[p], (p + 1 < NT) ? v[p + 1] : 0.0f);
                int col0 = p * 16 + c;
                if (col0 < NCOLS) hp[col0] = (unsigned char)(wrd & 0xFFu);
                if (p + 1 < NT) {
                    int col1 = col0 + 16;
                    if (col1 < NCOLS) hp[col1] = (unsigned char)((wrd >> 8) & 0xFFu);
                }
            }
        }
    }
}

// Layer-1 aggregate (F=64 fp8): ONE 8-LANE GROUP PER NODE (8 nodes/wave).
__global__ void __launch_bounds__(256)
k_gather_relu(const int* __restrict__ rowst, const int* __restrict__ csr,
              const unsigned char* __restrict__ h1s, const float* __restrict__ dinv,
              const float* __restrict__ b, unsigned short* __restrict__ out, int n) {
    long long gid = (long long)blockIdx.x * blockDim.x + threadIdx.x;
    int node = (int)(gid >> 3);
    int fe   = (int)(gid & 7);
    if (node >= n) return;          // group-uniform
    int jb = rowst[node], je = rowst[node + 1];
    unsigned feoff = (unsigned)fe << 3;

    f32x2 a0[4], a1[4];
#pragma unroll
    for (int q = 0; q < 4; ++q) { a0[q] = (f32x2){0.f, 0.f}; a1[q] = (f32x2){0.f, 0.f}; }

    int j = jb;
    for (; j + 1 < je; j += 2) {
        int s0 = csr[j];
        int s1 = csr[j + 1];
        uint2 u0 = *(const uint2*)(h1s + (((unsigned)s0 << 6) + feoff));
        uint2 u1 = *(const uint2*)(h1s + (((unsigned)s1 << 6) + feoff));
        acc8(a0, u0);
        acc8(a1, u1);
    }
    if (j < je) {
        int s0 = csr[j];
        uint2 u0 = *(const uint2*)(h1s + (((unsigned)s0 << 6) + feoff));
        acc8(a0, u0);
    }
#pragma unroll
    for (int q = 0; q < 4; ++q) a0[q] += a1[q];

    uint2 self = *(const uint2*)(h1s + (((unsigned)node << 6) + feoff));
    acc8(a0, self);
    float di = dinv[node];
    unsigned short r[8];
#pragma unroll
    for (int q = 0; q < 4; ++q) {
        float v0 = fmaxf(a0[q].x * di + b[8 * fe + 2 * q],     0.0f);
        float v1 = fmaxf(a0[q].y * di + b[8 * fe + 2 * q + 1], 0.0f);
        r[2 * q]     = (unsigned short)f2bf(v0);
        r[2 * q + 1] = (unsigned short)f2bf(v1);
    }
    uint4 pk;
    pk.x = (unsigned)r[0] | ((unsigned)r[1] << 16);
    pk.y = (unsigned)r[2] | ((unsigned)r[3] << 16);
    pk.z = (unsigned)r[4] | ((unsigned)r[5] << 16);
    pk.w = (unsigned)r[6] | ((unsigned)r[7] << 16);
    ((uint4*)(out + (long long)node * 64))[fe] = pk;
}

// Layer-2 aggregate + bias + log_softmax (F=40 fp8 in, fp32 out).
__global__ void __launch_bounds__(256)
k_gather_lsm(const int* __restrict__ rowst, const int* __restrict__ csr,
             const unsigned char* __restrict__ h2s, const float* __restrict__ dinv,
             const float* __restrict__ b, float* __restrict__ out, int n) {
    long long gid = (long long)blockIdx.x * blockDim.x + threadIdx.x;
    int node = (int)(gid >> 3);
    int fe   = (int)(gid & 7);
    if (node >= n) return;          // group-uniform
    bool act = (fe < 5);
    int jb = rowst[node], je = rowst[node + 1];
    unsigned feoff = (unsigned)fe << 3;

    f32x2 a0[4], a1[4];
#pragma unroll
    for (int q = 0; q < 4; ++q) { a0[q] = (f32x2){0.f, 0.f}; a1[q] = (f32x2){0.f, 0.f}; }

    int j = jb;
    for (; j + 1 < je; j += 2) {
        int s0 = csr[j];
        int s1 = csr[j + 1];
        if (act) {
            uint2 u0 = *(const uint2*)(h2s + ((unsigned)s0 * 40u + feoff));
            uint2 u1 = *(const uint2*)(h2s + ((unsigned)s1 * 40u + feoff));
            acc8(a0, u0);
            acc8(a1, u1);
        }
    }
    if (j < je && act) {
        int s0 = csr[j];
        uint2 u0 = *(const uint2*)(h2s + ((unsigned)s0 * 40u + feoff));
        acc8(a0, u0);
    }
#pragma unroll
    for (int q = 0; q < 4; ++q) a0[q] += a1[q];

    float va[8];
    float mloc = -INFINITY;
    if (act) {
        uint2 self = *(const uint2*)(h2s + ((unsigned)node * 40u + feoff));
        acc8(a0, self);
        float di = dinv[node];
#pragma unroll
        for (int q = 0; q < 4; ++q) {
            va[2 * q]     = a0[q].x * di + b[8 * fe + 2 * q];
            va[2 * q + 1] = a0[q].y * di + b[8 * fe + 2 * q + 1];
            mloc = fmaxf(mloc, fmaxf(va[2 * q], va[2 * q + 1]));
        }
    }
    float m = mloc;
    m = fmaxf(m, __shfl_xor(m, 1));
    m = fmaxf(m, __shfl_xor(m, 2));
    m = fmaxf(m, __shfl_xor(m, 4));
    float ex = 0.0f;
    if (act) {
#pragma unroll
        for (int k = 0; k < 8; ++k) ex += __expf(va[k] - m);
    }
    ex += __shfl_xor(ex, 1);
    ex += __shfl_xor(ex, 2);
    ex += __shfl_xor(ex, 4);
    float lse = __logf(ex);
    if (act) {
        float4 r0 = make_float4(va[0] - m - lse, va[1] - m - lse,
                                va[2] - m - lse, va[3] - m - lse);
        float4 r1 = make_float4(va[4] - m - lse, va[5] - m - lse,
                                va[6] - m - lse, va[7] - m - lse);
        *(float4*)(out + (long long)node * 40 + 8 * fe)     = r0;
        *(float4*)(out + (long long)node * 40 + 8 * fe + 4) = r1;
    }
}

extern "C" void kernel_launch(void* const* d_in, const int* in_sizes, int n_in,
                              void* d_out, int out_size, void* d_ws, size_t ws_size,
                              hipStream_t stream) {
    const float* x  = (const float*)d_in[0];
    const void*  ei = d_in[1];
    const float* W1 = (const float*)d_in[2];
    const float* b1 = (const float*)d_in[3];
    const float* W2 = (const float*)d_in[4];
    const float* b2 = (const float*)d_in[5];
    float* out = (float*)d_out;

    const long long E = (long long)in_sizes[1] / 2;   // 3,200,000
    const int nblk = (int)((E + EPB - 1) / EPB);      // 391

    char* w = (char*)d_ws;
    auto alloc = [&](size_t bytes) -> void* {
        void* p = (void*)w;
        w += (bytes + 255) & ~(size_t)255;
        return p;
    };
    int*      flag    = (int*)     alloc(4);
    int*      gcur    = (int*)     alloc((size_t)NBUCK * 4);
    int*      bstart  = (int*)     alloc(((size_t)NBUCK + 1) * 4);
    int*      rowst   = (int*)     alloc(((size_t)NN + 1) * 4);
    float*    dinv    = (float*)   alloc((size_t)NN * 4);
    short*    pB1     = (short*)   alloc((size_t)8 * 4 * 64 * 8 * 2);   // 32 KB
    short*    pB2     = (short*)   alloc((size_t)2 * 3 * 64 * 8 * 2);   // 6 KB
    int*      csr     = (int*)     alloc((size_t)E * 4);
    unsigned* ebuf    = (unsigned*)alloc((size_t)NBUCK * CAP * 4);   // 19.3 MB
    unsigned short* agg1 = (unsigned short*)alloc((size_t)NN * 64 * 2);
    unsigned char* h1s = (unsigned char*)ebuf;   // ebuf dead before gemm1 writes h1s
    unsigned char* h2s = h1s;                    // h1s dead after k_gather_relu

    const int B = 256;
    auto cdiv = [](long long a, long long b) { return (int)((a + b - 1) / b); };

    // 0) fused init: dtype detect + gcur zero + weight packing (one launch)
    k_init<<<11, B, 0, stream>>>((const unsigned int*)ei, flag, gcur, W1, pB1, W2, pB2);

    // 1) one-pass bucketed edge scatter + per-bucket CSR build (+ dinv)
    k_scatter_bucket<<<nblk, SCT, 0, stream>>>(ei, flag, E, gcur, ebuf);
    k_bucket_starts<<<1, 64, 0, stream>>>(gcur, bstart, rowst, NN);
    k_bucket_csr<<<NBUCK, 1024, 0, stream>>>(ebuf, gcur, bstart, rowst, dinv, csr);

    // 2) h1s = fp8( (x @ W1) * dinv[row] )   via bf16 MFMA
    k_mfma_gemm<256, 64, 8, 4, false><<<cdiv(NN, 64), B, 0, stream>>>(x, pB1, dinv, h1s, NN);

    // 3) layer-1 aggregate + bias + ReLU  (fp8 in -> bf16 out), 8 nodes/wave
    k_gather_relu<<<cdiv((long long)NN * 8, B), B, 0, stream>>>(rowst, csr, h1s, dinv, b1, agg1, NN);

    // 4) h2s = fp8( (agg1 @ W2) * dinv[row] )  via bf16 MFMA, bf16 A
    k_mfma_gemm<64, 40, 2, 3, true><<<cdiv(NN, 64), B, 0, stream>>>(agg1, pB2, dinv, h2s, NN);

    // 5) layer-2 aggregate + bias + log_softmax -> d_out (fp32), 8 nodes/wave
    k_gather_lsm<<<cdiv((long long)NN * 8, B), B, 0, stream>>>(rowst, csr, h2s, dinv, b2, out, NN);
}

// Round 15
// 192.881 us; speedup vs baseline: 1.1763x; 1.0026x over previous
//
#include <hip/hip_runtime.h>
#include <hip/hip_bf16.h>
#include <math.h>

static constexpr int NN    = 100000;            // N_NODES
static constexpr int BSH   = 9;                 // bucket covers 512 nodes
static constexpr int NBUCK = (NN + 511) >> 9;   // 196
static constexpr int EPB   = 8192;              // edges per scatter block
static constexpr int CAP   = 24576;             // per-bucket region capacity (avg 16.3k)

typedef __attribute__((ext_vector_type(8))) short short8;
typedef __attribute__((ext_vector_type(4))) float f32x4;
typedef __attribute__((ext_vector_type(2))) float f32x2;

// HW fp8 conversion (gfx950). Word-select args must be IMMEDIATE constants.
#if defined(__has_builtin)
#  if __has_builtin(__builtin_amdgcn_cvt_pk_f32_fp8) && __has_builtin(__builtin_amdgcn_cvt_pk_fp8_f32)
#    define USE_HW_FP8 1
#  endif
#endif
#ifndef USE_HW_FP8
#  define USE_HW_FP8 0
#endif

__device__ __forceinline__ short f2bf(float f) {
    __hip_bfloat16 h = __float2bfloat16(f);
    return __builtin_bit_cast(short, h);
}

// ---- software fp8 e4m3 (fallback only) ----
__device__ __forceinline__ float fp8_dec_sw(unsigned b) {
    unsigned u = ((b & 0x80u) << 24) | ((b & 0x7Fu) << 20);
    return __builtin_bit_cast(float, u) * 0x1p120f;
}
__device__ __forceinline__ unsigned fp8_enc_sw(float f) {
    unsigned u = __builtin_bit_cast(unsigned, f * 0x1p-120f);
    unsigned s = (u >> 24) & 0x80u;
    unsigned mag = u & 0x7FFFFFFFu;
    unsigned t = mag + 0x7FFFFu + ((mag >> 20) & 1u);
    unsigned r = t >> 20;
    if (r > 0x7Eu) r = 0x7Eu;
    return s | r;
}

template<bool HI>
__device__ __forceinline__ f32x2 dec2w(unsigned u) {
#if USE_HW_FP8
    return __builtin_amdgcn_cvt_pk_f32_fp8(u, HI);
#else
    unsigned w = HI ? (u >> 16) : u;
    f32x2 r;
    r.x = fp8_dec_sw(w & 0xFFu);
    r.y = fp8_dec_sw((w >> 8) & 0xFFu);
    return r;
#endif
}
__device__ __forceinline__ unsigned enc2(float a, float b) {
#if USE_HW_FP8
    return (unsigned)__builtin_amdgcn_cvt_pk_fp8_f32(a, b, 0, false);
#else
    return fp8_enc_sw(a) | (fp8_enc_sw(b) << 8);
#endif
}

// accumulate 8 fp8 (uint2) into f32x2 a[4]
__device__ __forceinline__ void acc8(f32x2* a, uint2 u) {
    a[0] += dec2w<false>(u.x);
    a[1] += dec2w<true>(u.x);
    a[2] += dec2w<false>(u.y);
    a[3] += dec2w<true>(u.y);
}
// fma-accumulate 8 fp8 scaled by ds
__device__ __forceinline__ void acc8s(f32x2* a, uint2 u, float ds) {
    f32x2 w = {ds, ds};
    a[0] = dec2w<false>(u.x) * w + a[0];
    a[1] = dec2w<true>(u.x)  * w + a[1];
    a[2] = dec2w<false>(u.y) * w + a[2];
    a[3] = dec2w<true>(u.y)  * w + a[3];
}

// ---- edge index load ----
__device__ __forceinline__ long long ldidx(const void* __restrict__ p, long long i, int is64) {
    if (is64) return ((const long long* __restrict__)p)[i];
    return (long long)((const int* __restrict__)p)[i];
}

// ---- weight pack (device helper) ----
template<int K, int NCOLS, int KT, int NT>
__device__ __forceinline__ void packB_dev(const float* __restrict__ W,
                                          short* __restrict__ P, int t) {
    if (t >= KT * NT * 64) return;
    int kt = t / (NT * 64);
    int nt = (t / 64) % NT;
    int l  = t & 63;
    int g  = l >> 4;
#pragma unroll
    for (int e = 0; e < 8; ++e) {
        int k   = kt * 32 + g * 8 + e;
        int col = nt * 16 + (l & 15);
        float v = (col < NCOLS) ? W[k * NCOLS + col] : 0.0f;
        P[t * 8 + e] = f2bf(v);
    }
}

// Fused init: block 0 = dtype-detect + gcur zero; blocks 1-8 = packB1; 9-10 = packB2.
__global__ void __launch_bounds__(256)
k_init(const unsigned int* __restrict__ e32, int* __restrict__ flag,
       int* __restrict__ gcur,
       const float* __restrict__ W1, short* __restrict__ pB1,
       const float* __restrict__ W2, short* __restrict__ pB2) {
    int blk = blockIdx.x, tid = threadIdx.x;
    if (blk == 0) {
        if (tid < NBUCK) gcur[tid] = 0;
        __shared__ int any_nz;
        if (tid == 0) any_nz = 0;
        __syncthreads();
        unsigned int nz = 0;
        for (int w = 1 + 2 * tid; w < 4096; w += 512)
            nz |= e32[w];
        if (nz) atomicOr(&any_nz, 1);
        __syncthreads();
        if (tid == 0) *flag = (any_nz == 0) ? 1 : 0;   // 1 => int64
    } else if (blk <= 8) {
        packB_dev<256, 64, 8, 4>(W1, pB1, (blk - 1) * 256 + tid);
    } else {
        packB_dev<64, 40, 2, 3>(W2, pB2, (blk - 9) * 256 + tid);
    }
}

// ---- FUSED: bucketed edge scatter (blocks < nsblk) + gemm1 (blocks >= nsblk) ----
// Independent phases co-scheduled in one launch: scatter is latency/atomic-bound,
// gemm1 is HBM/MFMA-bound -> overlap. gemm1 writes h1s UNSCALED fp8 (dinv applied
// per-edge in the gather; fp8 relative error is scale-invariant).
__global__ void __launch_bounds__(1024)
k_build_gemm1(const void* __restrict__ eidx, const int* __restrict__ flag, long long E,
              int nsblk, int* __restrict__ gcur, unsigned* __restrict__ ebuf,
              const float* __restrict__ X, const short* __restrict__ pB1,
              unsigned char* __restrict__ H, int n) {
    if ((int)blockIdx.x < nsblk) {
        // ---- scatter half (register-cached edges, 8 per thread) ----
        __shared__ int h[NBUCK];
        for (int b = threadIdx.x; b < NBUCK; b += 1024) h[b] = 0;
        __syncthreads();
        int is64 = *flag;
        long long base = (long long)blockIdx.x * EPB;
        long long end  = base + EPB < E ? base + EPB : E;
        unsigned sv[8], dv[8];
        bool ok[8];
#pragma unroll
        for (int k = 0; k < 8; ++k) {
            long long e = base + (long long)k * 1024 + threadIdx.x;
            ok[k] = (e < end);
            if (ok[k]) {
                sv[k] = (unsigned)ldidx(eidx, e, is64);
                dv[k] = (unsigned)ldidx(eidx, E + e, is64);
                atomicAdd(&h[dv[k] >> BSH], 1);
            }
        }
        __syncthreads();
        for (int b = threadIdx.x; b < NBUCK; b += 1024)
            h[b] = atomicAdd(&gcur[b], h[b]);
        __syncthreads();
#pragma unroll
        for (int k = 0; k < 8; ++k) {
            if (ok[k]) {
                int bk = dv[k] >> BSH;
                int pos = atomicAdd(&h[bk], 1);
                ebuf[(long long)bk * CAP + pos] = sv[k] | ((dv[k] & 511u) << 17);
            }
        }
    } else {
        // ---- gemm1 half: 16 waves, 16 rows/wave = 256 rows/block ----
        __shared__ alignas(16) short sW[8 * 4 * 512];   // 32 KB packed W1
        short8* dst = (short8*)sW;
        const short8* src = (const short8*)pB1;
        int tid = threadIdx.x;
        for (int i = tid; i < 2048; i += 1024) dst[i] = src[i];
        __syncthreads();

        int gblk = (int)blockIdx.x - nsblk;
        int wave = tid >> 6, lane = tid & 63;
        int g = lane >> 4;
        int arow = gblk * 256 + wave * 16 + (lane & 15);

        f32x4 acc[4];
#pragma unroll
        for (int nt = 0; nt < 4; ++nt) acc[nt] = (f32x4){0.f, 0.f, 0.f, 0.f};

#pragma unroll
        for (int kt = 0; kt < 8; ++kt) {
            short8 a;
            if (arow < n) {
                const float* xr = X + (long long)arow * 256;
                int k0 = kt * 32 + g * 8;
                float4 u = *(const float4*)(xr + k0);
                float4 v = *(const float4*)(xr + k0 + 4);
                a[0] = f2bf(u.x); a[1] = f2bf(u.y); a[2] = f2bf(u.z); a[3] = f2bf(u.w);
                a[4] = f2bf(v.x); a[5] = f2bf(v.y); a[6] = f2bf(v.z); a[7] = f2bf(v.w);
            } else {
                a = (short8){0, 0, 0, 0, 0, 0, 0, 0};
            }
#pragma unroll
            for (int nt = 0; nt < 4; ++nt) {
                short8 bfr = dst[(kt * 4 + nt) * 64 + lane];
                acc[nt] = __builtin_amdgcn_mfma_f32_16x16x32_bf16(a, bfr, acc[nt], 0, 0, 0);
            }
        }

        // C/D layout: col = lane&15, row = (lane>>4)*4 + reg. NCOLS=64 (all valid).
        int c = lane & 15;
        int orow_base = gblk * 256 + wave * 16 + g * 4;
#pragma unroll
        for (int r = 0; r < 4; ++r) {
            int orow = orow_base + r;
            if (orow < n) {
                unsigned char* hp = H + (long long)orow * 64;
#pragma unroll
                for (int p = 0; p < 4; p += 2) {
                    unsigned wrd = enc2(acc[p][r], acc[p + 1][r]);
                    hp[p * 16 + c]        = (unsigned char)(wrd & 0xFFu);
                    hp[(p + 1) * 16 + c]  = (unsigned char)((wrd >> 8) & 0xFFu);
                }
            }
        }
    }
}

// per bucket (512 nodes), 1024 threads: inline bucket-prefix, counts in LDS,
// wave-shuffle scan, emit rowst/dinv/csr.
__global__ void __launch_bounds__(1024)
k_bucket_csr(const unsigned* __restrict__ ebuf, const int* __restrict__ gcnt,
             int* __restrict__ rowst, float* __restrict__ dinv,
             int* __restrict__ csr, int n) {
    __shared__ int cnt[512];
    __shared__ int cursor[512];
    __shared__ int woff[8];
    __shared__ int bs_sh;
    int b = blockIdx.x;
    int t = threadIdx.x;
    int cb = gcnt[b];
    long long rbase = (long long)b * CAP;
    if (t == 0) bs_sh = 0;
    if (t < 512) cnt[t] = 0;
    __syncthreads();
    if (t < b) atomicAdd(&bs_sh, gcnt[t]);   // b <= 195 < 1024: full coverage
    for (int i = t; i < cb; i += 1024) {
        unsigned ed = ebuf[rbase + i];
        atomicAdd(&cnt[ed >> 17], 1);
    }
    __syncthreads();
    int bs = bs_sh;
    if (b == NBUCK - 1 && t == 0) rowst[n] = bs + cb;   // == E
    int v = 0, ps = 0;
    if (t < 512) {
        v = cnt[t];
        ps = v;
        int lane = t & 63;
#pragma unroll
        for (int off = 1; off < 64; off <<= 1) {
            int up = __shfl_up(ps, off);
            if (lane >= off) ps += up;
        }
        if (lane == 63) woff[t >> 6] = ps;   // wave inclusive total
    }
    __syncthreads();
    if (t == 0) {
        int run = 0;
#pragma unroll
        for (int i = 0; i < 8; ++i) { int x = woff[i]; woff[i] = run; run += x; }
    }
    __syncthreads();
    if (t < 512) {
        int incl  = ps + woff[t >> 6];
        int start = bs + incl - v;           // exclusive
        int gnode = (b << BSH) + t;
        if (gnode < n) {
            rowst[gnode] = start;
            dinv[gnode]  = rsqrtf((float)(v + 1));
        }
        cursor[t] = start;
    }
    __syncthreads();
    for (int i = t; i < cb; i += 1024) {
        unsigned ed = ebuf[rbase + i];
        int pos = atomicAdd(&cursor[ed >> 17], 1);
        csr[pos] = (int)(ed & 0x1FFFFu);
    }
}

// H[i,:] = fp8( (X[i,:K] @ W) * dinv[i] ), fp32 accumulate via bf16 MFMA. (gemm2)
template<int K, int NCOLS, int KT, int NT, bool ABF16>
__global__ void __launch_bounds__(256)
k_mfma_gemm(const void* __restrict__ Xv, const short* __restrict__ packedB,
            const float* __restrict__ dinv, unsigned char* __restrict__ H, int n) {
    __shared__ alignas(16) short sW[KT * NT * 512];
    short8* dst = (short8*)sW;
    const short8* src = (const short8*)packedB;
    constexpr int TOT8 = KT * NT * 64;
    for (int i = threadIdx.x; i < TOT8; i += 256) dst[i] = src[i];
    __syncthreads();

    int wave = threadIdx.x >> 6, lane = threadIdx.x & 63;
    int g = lane >> 4;
    int arow = blockIdx.x * 64 + wave * 16 + (lane & 15);

    f32x4 acc[NT];
#pragma unroll
    for (int nt = 0; nt < NT; ++nt) acc[nt] = (f32x4){0.f, 0.f, 0.f, 0.f};

#pragma unroll
    for (int kt = 0; kt < KT; ++kt) {
        short8 a;
        if (arow < n) {
            int k0 = kt * 32 + g * 8;
            if (ABF16) {
                const short* xr = (const short*)Xv + (long long)arow * K;
                a = *(const short8*)(xr + k0);
            } else {
                const float* xr = (const float*)Xv + (long long)arow * K;
                float4 u = *(const float4*)(xr + k0);
                float4 v = *(const float4*)(xr + k0 + 4);
                a[0] = f2bf(u.x); a[1] = f2bf(u.y); a[2] = f2bf(u.z); a[3] = f2bf(u.w);
                a[4] = f2bf(v.x); a[5] = f2bf(v.y); a[6] = f2bf(v.z); a[7] = f2bf(v.w);
            }
        } else {
            a = (short8){0, 0, 0, 0, 0, 0, 0, 0};
        }
#pragma unroll
        for (int nt = 0; nt < NT; ++nt) {
            short8 bfr = dst[(kt * NT + nt) * 64 + lane];
            acc[nt] = __builtin_amdgcn_mfma_f32_16x16x32_bf16(a, bfr, acc[nt], 0, 0, 0);
        }
    }

    int c = lane & 15;
    int orow_base = blockIdx.x * 64 + wave * 16 + g * 4;
#pragma unroll
    for (int r = 0; r < 4; ++r) {
        int orow = orow_base + r;
        if (orow < n) {
            float di = dinv[orow];
            float v[NT];
#pragma unroll
            for (int nt = 0; nt < NT; ++nt) v[nt] = acc[nt][r] * di;
            unsigned char* hp = H + (long long)orow * NCOLS;
#pragma unroll
            for (int p = 0; p < NT; p += 2) {
                unsigned wrd = enc2(v[p], (p + 1 < NT) ? v[p + 1] : 0.0f);
                int col0 = p * 16 + c;
                if (col0 < NCOLS) hp[col0] = (unsigned char)(wrd & 0xFFu);
                if (p + 1 < NT) {
                    int col1 = col0 + 16;
                    if (col1 < NCOLS) hp[col1] = (unsigned char)((wrd >> 8) & 0xFFu);
                }
            }
        }
    }
}

// Layer-1 aggregate (F=64 fp8, UNSCALED h1): ONE 8-LANE GROUP PER NODE.
// acc = Sum h1[s]*dinv[s] (pk-fma) + h1[node]*dinv[node]; out = acc*dinv[node]+b.
__global__ void __launch_bounds__(256)
k_gather_relu(const int* __restrict__ rowst, const int* __restrict__ csr,
              const unsigned char* __restrict__ h1s, const float* __restrict__ dinv,
              const float* __restrict__ b, unsigned short* __restrict__ out, int n) {
    long long gid = (long long)blockIdx.x * blockDim.x + threadIdx.x;
    int node = (int)(gid >> 3);
    int fe   = (int)(gid & 7);
    if (node >= n) return;          // group-uniform
    int jb = rowst[node], je = rowst[node + 1];
    unsigned feoff = (unsigned)fe << 3;

    f32x2 a0[4], a1[4];
#pragma unroll
    for (int q = 0; q < 4; ++q) { a0[q] = (f32x2){0.f, 0.f}; a1[q] = (f32x2){0.f, 0.f}; }

    int j = jb;
    for (; j + 1 < je; j += 2) {
        int s0 = csr[j];
        int s1 = csr[j + 1];
        float ds0 = dinv[s0];
        float ds1 = dinv[s1];
        uint2 u0 = *(const uint2*)(h1s + (((unsigned)s0 << 6) + feoff));
        uint2 u1 = *(const uint2*)(h1s + (((unsigned)s1 << 6) + feoff));
        acc8s(a0, u0, ds0);
        acc8s(a1, u1, ds1);
    }
    if (j < je) {
        int s0 = csr[j];
        float ds0 = dinv[s0];
        uint2 u0 = *(const uint2*)(h1s + (((unsigned)s0 << 6) + feoff));
        acc8s(a0, u0, ds0);
    }
#pragma unroll
    for (int q = 0; q < 4; ++q) a0[q] += a1[q];

    float dn = dinv[node];
    uint2 self = *(const uint2*)(h1s + (((unsigned)node << 6) + feoff));
    acc8s(a0, self, dn);
    unsigned short r[8];
#pragma unroll
    for (int q = 0; q < 4; ++q) {
        float v0 = fmaxf(a0[q].x * dn + b[8 * fe + 2 * q],     0.0f);
        float v1 = fmaxf(a0[q].y * dn + b[8 * fe + 2 * q + 1], 0.0f);
        r[2 * q]     = (unsigned short)f2bf(v0);
        r[2 * q + 1] = (unsigned short)f2bf(v1);
    }
    uint4 pk;
    pk.x = (unsigned)r[0] | ((unsigned)r[1] << 16);
    pk.y = (unsigned)r[2] | ((unsigned)r[3] << 16);
    pk.z = (unsigned)r[4] | ((unsigned)r[5] << 16);
    pk.w = (unsigned)r[6] | ((unsigned)r[7] << 16);
    ((uint4*)(out + (long long)node * 64))[fe] = pk;
}

// Layer-2 aggregate + bias + log_softmax (F=40 fp8 in, scaled; fp32 out).
__global__ void __launch_bounds__(256)
k_gather_lsm(const int* __restrict__ rowst, const int* __restrict__ csr,
             const unsigned char* __restrict__ h2s, const float* __restrict__ dinv,
             const float* __restrict__ b, float* __restrict__ out, int n) {
    long long gid = (long long)blockIdx.x * blockDim.x + threadIdx.x;
    int node = (int)(gid >> 3);
    int fe   = (int)(gid & 7);
    if (node >= n) return;          // group-uniform
    bool act = (fe < 5);
    int jb = rowst[node], je = rowst[node + 1];
    unsigned feoff = (unsigned)fe << 3;

    f32x2 a0[4], a1[4];
#pragma unroll
    for (int q = 0; q < 4; ++q) { a0[q] = (f32x2){0.f, 0.f}; a1[q] = (f32x2){0.f, 0.f}; }

    int j = jb;
    for (; j + 1 < je; j += 2) {
        int s0 = csr[j];
        int s1 = csr[j + 1];
        if (act) {
            uint2 u0 = *(const uint2*)(h2s + ((unsigned)s0 * 40u + feoff));
            uint2 u1 = *(const uint2*)(h2s + ((unsigned)s1 * 40u + feoff));
            acc8(a0, u0);
            acc8(a1, u1);
        }
    }
    if (j < je && act) {
        int s0 = csr[j];
        uint2 u0 = *(const uint2*)(h2s + ((unsigned)s0 * 40u + feoff));
        acc8(a0, u0);
    }
#pragma unroll
    for (int q = 0; q < 4; ++q) a0[q] += a1[q];

    float va[8];
    float mloc = -INFINITY;
    if (act) {
        uint2 self = *(const uint2*)(h2s + ((unsigned)node * 40u + feoff));
        acc8(a0, self);
        float di = dinv[node];
#pragma unroll
        for (int q = 0; q < 4; ++q) {
            va[2 * q]     = a0[q].x * di + b[8 * fe + 2 * q];
            va[2 * q + 1] = a0[q].y * di + b[8 * fe + 2 * q + 1];
            mloc = fmaxf(mloc, fmaxf(va[2 * q], va[2 * q + 1]));
        }
    }
    float m = mloc;
    m = fmaxf(m, __shfl_xor(m, 1));
    m = fmaxf(m, __shfl_xor(m, 2));
    m = fmaxf(m, __shfl_xor(m, 4));
    float ex = 0.0f;
    if (act) {
#pragma unroll
        for (int k = 0; k < 8; ++k) ex += __expf(va[k] - m);
    }
    ex += __shfl_xor(ex, 1);
    ex += __shfl_xor(ex, 2);
    ex += __shfl_xor(ex, 4);
    float lse = __logf(ex);
    if (act) {
        float4 r0 = make_float4(va[0] - m - lse, va[1] - m - lse,
                                va[2] - m - lse, va[3] - m - lse);
        float4 r1 = make_float4(va[4] - m - lse, va[5] - m - lse,
                                va[6] - m - lse, va[7] - m - lse);
        *(float4*)(out + (long long)node * 40 + 8 * fe)     = r0;
        *(float4*)(out + (long long)node * 40 + 8 * fe + 4) = r1;
    }
}

extern "C" void kernel_launch(void* const* d_in, const int* in_sizes, int n_in,
                              void* d_out, int out_size, void* d_ws, size_t ws_size,
                              hipStream_t stream) {
    const float* x  = (const float*)d_in[0];
    const void*  ei = d_in[1];
    const float* W1 = (const float*)d_in[2];
    const float* b1 = (const float*)d_in[3];
    const float* W2 = (const float*)d_in[4];
    const float* b2 = (const float*)d_in[5];
    float* out = (float*)d_out;

    const long long E = (long long)in_sizes[1] / 2;   // 3,200,000
    const int nsblk = (int)((E + EPB - 1) / EPB);     // 391 scatter blocks
    const int ngblk = (NN + 255) / 256;               // 391 gemm1 blocks

    char* w = (char*)d_ws;
    auto alloc = [&](size_t bytes) -> void* {
        void* p = (void*)w;
        w += (bytes + 255) & ~(size_t)255;
        return p;
    };
    int*      flag    = (int*)     alloc(4);
    int*      gcur    = (int*)     alloc((size_t)NBUCK * 4);
    int*      rowst   = (int*)     alloc(((size_t)NN + 1) * 4);
    float*    dinv    = (float*)   alloc((size_t)NN * 4);
    short*    pB1     = (short*)   alloc((size_t)8 * 4 * 64 * 8 * 2);   // 32 KB
    short*    pB2     = (short*)   alloc((size_t)2 * 3 * 64 * 8 * 2);   // 6 KB
    int*      csr     = (int*)     alloc((size_t)E * 4);
    unsigned* ebuf    = (unsigned*)alloc((size_t)NBUCK * CAP * 4);      // 19.3 MB
    unsigned char* h1s = (unsigned char*)alloc((size_t)NN * 64);        // 6.4 MB (NO alias: live with ebuf)
    unsigned short* agg1 = (unsigned short*)alloc((size_t)NN * 64 * 2);
    unsigned char* h2s = h1s;   // h1s dead after k_gather_relu

    const int B = 256;
    auto cdiv = [](long long a, long long b) { return (int)((a + b - 1) / b); };

    // 0) fused init: dtype detect + gcur zero + weight packing (one launch)
    k_init<<<11, B, 0, stream>>>((const unsigned int*)ei, flag, gcur, W1, pB1, W2, pB2);

    // 1) FUSED: edge scatter (blocks 0..390) + gemm1 unscaled (blocks 391..781)
    k_build_gemm1<<<nsblk + ngblk, 1024, 0, stream>>>(ei, flag, E, nsblk, gcur, ebuf,
                                                      x, pB1, h1s, NN);

    // 2) per-bucket CSR build (+ dinv, inline bucket-prefix)
    k_bucket_csr<<<NBUCK, 1024, 0, stream>>>(ebuf, gcur, rowst, dinv, csr, NN);

    // 3) layer-1 aggregate + bias + ReLU  (fp8 unscaled in -> bf16 out), 8 nodes/wave
    k_gather_relu<<<cdiv((long long)NN * 8, B), B, 0, stream>>>(rowst, csr, h1s, dinv, b1, agg1, NN);

    // 4) h2s = fp8( (agg1 @ W2) * dinv[row] )  via bf16 MFMA, bf16 A
    k_mfma_gemm<64, 40, 2, 3, true><<<cdiv(NN, 64), B, 0, stream>>>(agg1, pB2, dinv, h2s, NN);

    // 5) layer-2 aggregate + bias + log_softmax -> d_out (fp32), 8 nodes/wave
    k_gather_lsm<<<cdiv((long long)NN * 8, B), B, 0, stream>>>(rowst, csr, h2s, dinv, b2, out, NN);
}

// Round 16
// 180.027 us; speedup vs baseline: 1.2603x; 1.0714x over previous
//
#include <hip/hip_runtime.h>
#include <hip/hip_bf16.h>
#include <math.h>

static constexpr int NN    = 100000;            // N_NODES
static constexpr int BSH   = 9;                 // bucket covers 512 nodes
static constexpr int NBUCK = (NN + 511) >> 9;   // 196
static constexpr int EPB   = 8192;              // edges per scatter block
static constexpr int CAP   = 24576;             // per-bucket region capacity (avg 16.3k)

typedef __attribute__((ext_vector_type(8))) short short8;
typedef __attribute__((ext_vector_type(4))) float f32x4;
typedef __attribute__((ext_vector_type(2))) float f32x2;

// HW fp8 conversion (gfx950). Word-select args must be IMMEDIATE constants.
#if defined(__has_builtin)
#  if __has_builtin(__builtin_amdgcn_cvt_pk_f32_fp8) && __has_builtin(__builtin_amdgcn_cvt_pk_fp8_f32)
#    define USE_HW_FP8 1
#  endif
#endif
#ifndef USE_HW_FP8
#  define USE_HW_FP8 0
#endif

__device__ __forceinline__ short f2bf(float f) {
    __hip_bfloat16 h = __float2bfloat16(f);
    return __builtin_bit_cast(short, h);
}

// ---- software fp8 e4m3 (fallback only) ----
__device__ __forceinline__ float fp8_dec_sw(unsigned b) {
    unsigned u = ((b & 0x80u) << 24) | ((b & 0x7Fu) << 20);
    return __builtin_bit_cast(float, u) * 0x1p120f;
}
__device__ __forceinline__ unsigned fp8_enc_sw(float f) {
    unsigned u = __builtin_bit_cast(unsigned, f * 0x1p-120f);
    unsigned s = (u >> 24) & 0x80u;
    unsigned mag = u & 0x7FFFFFFFu;
    unsigned t = mag + 0x7FFFFu + ((mag >> 20) & 1u);
    unsigned r = t >> 20;
    if (r > 0x7Eu) r = 0x7Eu;
    return s | r;
}

template<bool HI>
__device__ __forceinline__ f32x2 dec2w(unsigned u) {
#if USE_HW_FP8
    return __builtin_amdgcn_cvt_pk_f32_fp8(u, HI);
#else
    unsigned w = HI ? (u >> 16) : u;
    f32x2 r;
    r.x = fp8_dec_sw(w & 0xFFu);
    r.y = fp8_dec_sw((w >> 8) & 0xFFu);
    return r;
#endif
}
__device__ __forceinline__ unsigned enc2(float a, float b) {
#if USE_HW_FP8
    return (unsigned)__builtin_amdgcn_cvt_pk_fp8_f32(a, b, 0, false);
#else
    return fp8_enc_sw(a) | (fp8_enc_sw(b) << 8);
#endif
}

// accumulate 8 fp8 (uint2) into f32x2 a[4]
__device__ __forceinline__ void acc8(f32x2* a, uint2 u) {
    a[0] += dec2w<false>(u.x);
    a[1] += dec2w<true>(u.x);
    a[2] += dec2w<false>(u.y);
    a[3] += dec2w<true>(u.y);
}
// fma-accumulate 8 fp8 scaled by ds
__device__ __forceinline__ void acc8s(f32x2* a, uint2 u, float ds) {
    f32x2 w = {ds, ds};
    a[0] = dec2w<false>(u.x) * w + a[0];
    a[1] = dec2w<true>(u.x)  * w + a[1];
    a[2] = dec2w<false>(u.y) * w + a[2];
    a[3] = dec2w<true>(u.y)  * w + a[3];
}

// ---- edge index load ----
__device__ __forceinline__ long long ldidx(const void* __restrict__ p, long long i, int is64) {
    if (is64) return ((const long long* __restrict__)p)[i];
    return (long long)((const int* __restrict__)p)[i];
}

// ---- weight pack (device helper) ----
template<int K, int NCOLS, int KT, int NT>
__device__ __forceinline__ void packB_dev(const float* __restrict__ W,
                                          short* __restrict__ P, int t) {
    if (t >= KT * NT * 64) return;
    int kt = t / (NT * 64);
    int nt = (t / 64) % NT;
    int l  = t & 63;
    int g  = l >> 4;
#pragma unroll
    for (int e = 0; e < 8; ++e) {
        int k   = kt * 32 + g * 8 + e;
        int col = nt * 16 + (l & 15);
        float v = (col < NCOLS) ? W[k * NCOLS + col] : 0.0f;
        P[t * 8 + e] = f2bf(v);
    }
}

// Fused init: block 0 = dtype-detect + gcur zero; blocks 1-8 = packB1; 9-10 = packB2.
__global__ void __launch_bounds__(256)
k_init(const unsigned int* __restrict__ e32, int* __restrict__ flag,
       int* __restrict__ gcur,
       const float* __restrict__ W1, short* __restrict__ pB1,
       const float* __restrict__ W2, short* __restrict__ pB2) {
    int blk = blockIdx.x, tid = threadIdx.x;
    if (blk == 0) {
        if (tid < NBUCK) gcur[tid] = 0;
        __shared__ int any_nz;
        if (tid == 0) any_nz = 0;
        __syncthreads();
        unsigned int nz = 0;
        for (int w = 1 + 2 * tid; w < 4096; w += 512)
            nz |= e32[w];
        if (nz) atomicOr(&any_nz, 1);
        __syncthreads();
        if (tid == 0) *flag = (any_nz == 0) ? 1 : 0;   // 1 => int64
    } else if (blk <= 8) {
        packB_dev<256, 64, 8, 4>(W1, pB1, (blk - 1) * 256 + tid);
    } else {
        packB_dev<64, 40, 2, 3>(W2, pB2, (blk - 9) * 256 + tid);
    }
}

// ---- FUSED scatter + gemm1, CHECKERBOARD role mapping ----
// role = bid&1 while both kinds remain -> each CU co-hosts one scatter block
// (latency/LDS-atomic-bound) and one gemm block (MFMA/HBM-bound): true overlap.
__global__ void __launch_bounds__(1024)
k_build_gemm1(const void* __restrict__ eidx, const int* __restrict__ flag, long long E,
              int nsblk, int ngblk, int* __restrict__ gcur, unsigned* __restrict__ ebuf,
              const float* __restrict__ X, const short* __restrict__ pB1,
              unsigned char* __restrict__ H, int n) {
    int bid = (int)blockIdx.x;
    int mn = nsblk < ngblk ? nsblk : ngblk;
    int role, idx;
    if (bid < 2 * mn) { role = bid & 1; idx = bid >> 1; }
    else {
        int rem = bid - 2 * mn;
        role = (nsblk > ngblk) ? 0 : 1;
        idx = mn + rem;
    }
    if (role == 0) {
        // ---- scatter half (register-cached edges, 8 per thread) ----
        __shared__ int h[NBUCK];
        for (int b = threadIdx.x; b < NBUCK; b += 1024) h[b] = 0;
        __syncthreads();
        int is64 = *flag;
        long long base = (long long)idx * EPB;
        long long end  = base + EPB < E ? base + EPB : E;
        unsigned sv[8], dv[8];
        bool ok[8];
#pragma unroll
        for (int k = 0; k < 8; ++k) {
            long long e = base + (long long)k * 1024 + threadIdx.x;
            ok[k] = (e < end);
            if (ok[k]) {
                sv[k] = (unsigned)ldidx(eidx, e, is64);
                dv[k] = (unsigned)ldidx(eidx, E + e, is64);
                atomicAdd(&h[dv[k] >> BSH], 1);
            }
        }
        __syncthreads();
        for (int b = threadIdx.x; b < NBUCK; b += 1024)
            h[b] = atomicAdd(&gcur[b], h[b]);
        __syncthreads();
#pragma unroll
        for (int k = 0; k < 8; ++k) {
            if (ok[k]) {
                int bk = dv[k] >> BSH;
                int pos = atomicAdd(&h[bk], 1);
                ebuf[(long long)bk * CAP + pos] = sv[k] | ((dv[k] & 511u) << 17);
            }
        }
    } else {
        // ---- gemm1 half: 16 waves, 16 rows/wave = 256 rows/block ----
        __shared__ alignas(16) short sW[8 * 4 * 512];   // 32 KB packed W1
        short8* dst = (short8*)sW;
        const short8* src = (const short8*)pB1;
        int tid = threadIdx.x;
        for (int i = tid; i < 2048; i += 1024) dst[i] = src[i];
        __syncthreads();

        int wave = tid >> 6, lane = tid & 63;
        int g = lane >> 4;
        int arow = idx * 256 + wave * 16 + (lane & 15);

        f32x4 acc[4];
#pragma unroll
        for (int nt = 0; nt < 4; ++nt) acc[nt] = (f32x4){0.f, 0.f, 0.f, 0.f};

#pragma unroll
        for (int kt = 0; kt < 8; ++kt) {
            short8 a;
            if (arow < n) {
                const float* xr = X + (long long)arow * 256;
                int k0 = kt * 32 + g * 8;
                float4 u = *(const float4*)(xr + k0);
                float4 v = *(const float4*)(xr + k0 + 4);
                a[0] = f2bf(u.x); a[1] = f2bf(u.y); a[2] = f2bf(u.z); a[3] = f2bf(u.w);
                a[4] = f2bf(v.x); a[5] = f2bf(v.y); a[6] = f2bf(v.z); a[7] = f2bf(v.w);
            } else {
                a = (short8){0, 0, 0, 0, 0, 0, 0, 0};
            }
#pragma unroll
            for (int nt = 0; nt < 4; ++nt) {
                short8 bfr = dst[(kt * 4 + nt) * 64 + lane];
                acc[nt] = __builtin_amdgcn_mfma_f32_16x16x32_bf16(a, bfr, acc[nt], 0, 0, 0);
            }
        }

        // C/D layout: col = lane&15, row = (lane>>4)*4 + reg. NCOLS=64 (all valid).
        int c = lane & 15;
        int orow_base = idx * 256 + wave * 16 + g * 4;
#pragma unroll
        for (int r = 0; r < 4; ++r) {
            int orow = orow_base + r;
            if (orow < n) {
                unsigned char* hp = H + (long long)orow * 64;
#pragma unroll
                for (int p = 0; p < 4; p += 2) {
                    unsigned wrd = enc2(acc[p][r], acc[p + 1][r]);
                    hp[p * 16 + c]        = (unsigned char)(wrd & 0xFFu);
                    hp[(p + 1) * 16 + c]  = (unsigned char)((wrd >> 8) & 0xFFu);
                }
            }
        }
    }
}

// per bucket (512 nodes), 1024 threads: inline bucket-prefix, counts in LDS,
// wave-shuffle scan, emit rowst/dinv/csr.
__global__ void __launch_bounds__(1024)
k_bucket_csr(const unsigned* __restrict__ ebuf, const int* __restrict__ gcnt,
             int* __restrict__ rowst, float* __restrict__ dinv,
             int* __restrict__ csr, int n) {
    __shared__ int cnt[512];
    __shared__ int cursor[512];
    __shared__ int woff[8];
    __shared__ int bs_sh;
    int b = blockIdx.x;
    int t = threadIdx.x;
    int cb = gcnt[b];
    long long rbase = (long long)b * CAP;
    if (t == 0) bs_sh = 0;
    if (t < 512) cnt[t] = 0;
    __syncthreads();
    if (t < b) atomicAdd(&bs_sh, gcnt[t]);   // b <= 195 < 1024: full coverage
    for (int i = t; i < cb; i += 1024) {
        unsigned ed = ebuf[rbase + i];
        atomicAdd(&cnt[ed >> 17], 1);
    }
    __syncthreads();
    int bs = bs_sh;
    if (b == NBUCK - 1 && t == 0) rowst[n] = bs + cb;   // == E
    int v = 0, ps = 0;
    if (t < 512) {
        v = cnt[t];
        ps = v;
        int lane = t & 63;
#pragma unroll
        for (int off = 1; off < 64; off <<= 1) {
            int up = __shfl_up(ps, off);
            if (lane >= off) ps += up;
        }
        if (lane == 63) woff[t >> 6] = ps;   // wave inclusive total
    }
    __syncthreads();
    if (t == 0) {
        int run = 0;
#pragma unroll
        for (int i = 0; i < 8; ++i) { int x = woff[i]; woff[i] = run; run += x; }
    }
    __syncthreads();
    if (t < 512) {
        int incl  = ps + woff[t >> 6];
        int start = bs + incl - v;           // exclusive
        int gnode = (b << BSH) + t;
        if (gnode < n) {
            rowst[gnode] = start;
            dinv[gnode]  = rsqrtf((float)(v + 1));
        }
        cursor[t] = start;
    }
    __syncthreads();
    for (int i = t; i < cb; i += 1024) {
        unsigned ed = ebuf[rbase + i];
        int pos = atomicAdd(&cursor[ed >> 17], 1);
        csr[pos] = (int)(ed & 0x1FFFFu);
    }
}

// H[i,:] = fp8( (X[i,:K] @ W) * dinv[i] ), fp32 accumulate via bf16 MFMA. (gemm2)
template<int K, int NCOLS, int KT, int NT, bool ABF16>
__global__ void __launch_bounds__(256)
k_mfma_gemm(const void* __restrict__ Xv, const short* __restrict__ packedB,
            const float* __restrict__ dinv, unsigned char* __restrict__ H, int n) {
    __shared__ alignas(16) short sW[KT * NT * 512];
    short8* dst = (short8*)sW;
    const short8* src = (const short8*)packedB;
    constexpr int TOT8 = KT * NT * 64;
    for (int i = threadIdx.x; i < TOT8; i += 256) dst[i] = src[i];
    __syncthreads();

    int wave = threadIdx.x >> 6, lane = threadIdx.x & 63;
    int g = lane >> 4;
    int arow = blockIdx.x * 64 + wave * 16 + (lane & 15);

    f32x4 acc[NT];
#pragma unroll
    for (int nt = 0; nt < NT; ++nt) acc[nt] = (f32x4){0.f, 0.f, 0.f, 0.f};

#pragma unroll
    for (int kt = 0; kt < KT; ++kt) {
        short8 a;
        if (arow < n) {
            int k0 = kt * 32 + g * 8;
            if (ABF16) {
                const short* xr = (const short*)Xv + (long long)arow * K;
                a = *(const short8*)(xr + k0);
            } else {
                const float* xr = (const float*)Xv + (long long)arow * K;
                float4 u = *(const float4*)(xr + k0);
                float4 v = *(const float4*)(xr + k0 + 4);
                a[0] = f2bf(u.x); a[1] = f2bf(u.y); a[2] = f2bf(u.z); a[3] = f2bf(u.w);
                a[4] = f2bf(v.x); a[5] = f2bf(v.y); a[6] = f2bf(v.z); a[7] = f2bf(v.w);
            }
        } else {
            a = (short8){0, 0, 0, 0, 0, 0, 0, 0};
        }
#pragma unroll
        for (int nt = 0; nt < NT; ++nt) {
            short8 bfr = dst[(kt * NT + nt) * 64 + lane];
            acc[nt] = __builtin_amdgcn_mfma_f32_16x16x32_bf16(a, bfr, acc[nt], 0, 0, 0);
        }
    }

    int c = lane & 15;
    int orow_base = blockIdx.x * 64 + wave * 16 + g * 4;
#pragma unroll
    for (int r = 0; r < 4; ++r) {
        int orow = orow_base + r;
        if (orow < n) {
            float di = dinv[orow];
            float v[NT];
#pragma unroll
            for (int nt = 0; nt < NT; ++nt) v[nt] = acc[nt][r] * di;
            unsigned char* hp = H + (long long)orow * NCOLS;
#pragma unroll
            for (int p = 0; p < NT; p += 2) {
                unsigned wrd = enc2(v[p], (p + 1 < NT) ? v[p + 1] : 0.0f);
                int col0 = p * 16 + c;
                if (col0 < NCOLS) hp[col0] = (unsigned char)(wrd & 0xFFu);
                if (p + 1 < NT) {
                    int col1 = col0 + 16;
                    if (col1 < NCOLS) hp[col1] = (unsigned char)((wrd >> 8) & 0xFFu);
                }
            }
        }
    }
}

// Layer-1 aggregate (F=64 fp8, UNSCALED h1): ONE 8-LANE GROUP PER NODE.
// 4-deep unroll: 32 independent gathers in flight per wave.
__global__ void __launch_bounds__(256)
k_gather_relu(const int* __restrict__ rowst, const int* __restrict__ csr,
              const unsigned char* __restrict__ h1s, const float* __restrict__ dinv,
              const float* __restrict__ b, unsigned short* __restrict__ out, int n) {
    long long gid = (long long)blockIdx.x * blockDim.x + threadIdx.x;
    int node = (int)(gid >> 3);
    int fe   = (int)(gid & 7);
    if (node >= n) return;          // group-uniform
    int jb = rowst[node], je = rowst[node + 1];
    unsigned feoff = (unsigned)fe << 3;

    f32x2 a0[4], a1[4], a2[4], a3[4];
#pragma unroll
    for (int q = 0; q < 4; ++q) {
        a0[q] = (f32x2){0.f, 0.f}; a1[q] = (f32x2){0.f, 0.f};
        a2[q] = (f32x2){0.f, 0.f}; a3[q] = (f32x2){0.f, 0.f};
    }

    int j = jb;
    for (; j + 3 < je; j += 4) {
        int s0 = csr[j], s1 = csr[j + 1], s2 = csr[j + 2], s3 = csr[j + 3];
        float ds0 = dinv[s0], ds1 = dinv[s1], ds2 = dinv[s2], ds3 = dinv[s3];
        uint2 u0 = *(const uint2*)(h1s + (((unsigned)s0 << 6) + feoff));
        uint2 u1 = *(const uint2*)(h1s + (((unsigned)s1 << 6) + feoff));
        uint2 u2 = *(const uint2*)(h1s + (((unsigned)s2 << 6) + feoff));
        uint2 u3 = *(const uint2*)(h1s + (((unsigned)s3 << 6) + feoff));
        acc8s(a0, u0, ds0);
        acc8s(a1, u1, ds1);
        acc8s(a2, u2, ds2);
        acc8s(a3, u3, ds3);
    }
    for (; j < je; ++j) {
        int s0 = csr[j];
        float ds0 = dinv[s0];
        uint2 u0 = *(const uint2*)(h1s + (((unsigned)s0 << 6) + feoff));
        acc8s(a0, u0, ds0);
    }
#pragma unroll
    for (int q = 0; q < 4; ++q) a0[q] += (a1[q] + a2[q]) + a3[q];

    float dn = dinv[node];
    uint2 self = *(const uint2*)(h1s + (((unsigned)node << 6) + feoff));
    acc8s(a0, self, dn);
    unsigned short r[8];
#pragma unroll
    for (int q = 0; q < 4; ++q) {
        float v0 = fmaxf(a0[q].x * dn + b[8 * fe + 2 * q],     0.0f);
        float v1 = fmaxf(a0[q].y * dn + b[8 * fe + 2 * q + 1], 0.0f);
        r[2 * q]     = (unsigned short)f2bf(v0);
        r[2 * q + 1] = (unsigned short)f2bf(v1);
    }
    uint4 pk;
    pk.x = (unsigned)r[0] | ((unsigned)r[1] << 16);
    pk.y = (unsigned)r[2] | ((unsigned)r[3] << 16);
    pk.z = (unsigned)r[4] | ((unsigned)r[5] << 16);
    pk.w = (unsigned)r[6] | ((unsigned)r[7] << 16);
    ((uint4*)(out + (long long)node * 64))[fe] = pk;
}

// Layer-2 aggregate + bias + log_softmax (F=40 fp8 in, scaled; fp32 out).
// 4-deep unroll.
__global__ void __launch_bounds__(256)
k_gather_lsm(const int* __restrict__ rowst, const int* __restrict__ csr,
             const unsigned char* __restrict__ h2s, const float* __restrict__ dinv,
             const float* __restrict__ b, float* __restrict__ out, int n) {
    long long gid = (long long)blockIdx.x * blockDim.x + threadIdx.x;
    int node = (int)(gid >> 3);
    int fe   = (int)(gid & 7);
    if (node >= n) return;          // group-uniform
    bool act = (fe < 5);
    int jb = rowst[node], je = rowst[node + 1];
    unsigned feoff = (unsigned)fe << 3;

    f32x2 a0[4], a1[4], a2[4], a3[4];
#pragma unroll
    for (int q = 0; q < 4; ++q) {
        a0[q] = (f32x2){0.f, 0.f}; a1[q] = (f32x2){0.f, 0.f};
        a2[q] = (f32x2){0.f, 0.f}; a3[q] = (f32x2){0.f, 0.f};
    }

    int j = jb;
    for (; j + 3 < je; j += 4) {
        int s0 = csr[j], s1 = csr[j + 1], s2 = csr[j + 2], s3 = csr[j + 3];
        if (act) {
            uint2 u0 = *(const uint2*)(h2s + ((unsigned)s0 * 40u + feoff));
            uint2 u1 = *(const uint2*)(h2s + ((unsigned)s1 * 40u + feoff));
            uint2 u2 = *(const uint2*)(h2s + ((unsigned)s2 * 40u + feoff));
            uint2 u3 = *(const uint2*)(h2s + ((unsigned)s3 * 40u + feoff));
            acc8(a0, u0);
            acc8(a1, u1);
            acc8(a2, u2);
            acc8(a3, u3);
        }
    }
    for (; j < je; ++j) {
        int s0 = csr[j];
        if (act) {
            uint2 u0 = *(const uint2*)(h2s + ((unsigned)s0 * 40u + feoff));
            acc8(a0, u0);
        }
    }
#pragma unroll
    for (int q = 0; q < 4; ++q) a0[q] += (a1[q] + a2[q]) + a3[q];

    float va[8];
    float mloc = -INFINITY;
    if (act) {
        uint2 self = *(const uint2*)(h2s + ((unsigned)node * 40u + feoff));
        acc8(a0, self);
        float di = dinv[node];
#pragma unroll
        for (int q = 0; q < 4; ++q) {
            va[2 * q]     = a0[q].x * di + b[8 * fe + 2 * q];
            va[2 * q + 1] = a0[q].y * di + b[8 * fe + 2 * q + 1];
            mloc = fmaxf(mloc, fmaxf(va[2 * q], va[2 * q + 1]));
        }
    }
    float m = mloc;
    m = fmaxf(m, __shfl_xor(m, 1));
    m = fmaxf(m, __shfl_xor(m, 2));
    m = fmaxf(m, __shfl_xor(m, 4));
    float ex = 0.0f;
    if (act) {
#pragma unroll
        for (int k = 0; k < 8; ++k) ex += __expf(va[k] - m);
    }
    ex += __shfl_xor(ex, 1);
    ex += __shfl_xor(ex, 2);
    ex += __shfl_xor(ex, 4);
    float lse = __logf(ex);
    if (act) {
        float4 r0 = make_float4(va[0] - m - lse, va[1] - m - lse,
                                va[2] - m - lse, va[3] - m - lse);
        float4 r1 = make_float4(va[4] - m - lse, va[5] - m - lse,
                                va[6] - m - lse, va[7] - m - lse);
        *(float4*)(out + (long long)node * 40 + 8 * fe)     = r0;
        *(float4*)(out + (long long)node * 40 + 8 * fe + 4) = r1;
    }
}

extern "C" void kernel_launch(void* const* d_in, const int* in_sizes, int n_in,
                              void* d_out, int out_size, void* d_ws, size_t ws_size,
                              hipStream_t stream) {
    const float* x  = (const float*)d_in[0];
    const void*  ei = d_in[1];
    const float* W1 = (const float*)d_in[2];
    const float* b1 = (const float*)d_in[3];
    const float* W2 = (const float*)d_in[4];
    const float* b2 = (const float*)d_in[5];
    float* out = (float*)d_out;

    const long long E = (long long)in_sizes[1] / 2;   // 3,200,000
    const int nsblk = (int)((E + EPB - 1) / EPB);     // 391 scatter blocks
    const int ngblk = (NN + 255) / 256;               // 391 gemm1 blocks

    char* w = (char*)d_ws;
    auto alloc = [&](size_t bytes) -> void* {
        void* p = (void*)w;
        w += (bytes + 255) & ~(size_t)255;
        return p;
    };
    int*      flag    = (int*)     alloc(4);
    int*      gcur    = (int*)     alloc((size_t)NBUCK * 4);
    int*      rowst   = (int*)     alloc(((size_t)NN + 1) * 4);
    float*    dinv    = (float*)   alloc((size_t)NN * 4);
    short*    pB1     = (short*)   alloc((size_t)8 * 4 * 64 * 8 * 2);   // 32 KB
    short*    pB2     = (short*)   alloc((size_t)2 * 3 * 64 * 8 * 2);   // 6 KB
    int*      csr     = (int*)     alloc((size_t)E * 4);
    unsigned* ebuf    = (unsigned*)alloc((size_t)NBUCK * CAP * 4);      // 19.3 MB
    unsigned char* h1s = (unsigned char*)alloc((size_t)NN * 64);        // 6.4 MB (live with ebuf)
    unsigned short* agg1 = (unsigned short*)alloc((size_t)NN * 64 * 2);
    unsigned char* h2s = h1s;   // h1s dead after k_gather_relu

    const int B = 256;
    auto cdiv = [](long long a, long long b) { return (int)((a + b - 1) / b); };

    // 0) fused init: dtype detect + gcur zero + weight packing (one launch)
    k_init<<<11, B, 0, stream>>>((const unsigned int*)ei, flag, gcur, W1, pB1, W2, pB2);

    // 1) FUSED checkerboard: edge scatter + gemm1 (unscaled fp8 out)
    k_build_gemm1<<<nsblk + ngblk, 1024, 0, stream>>>(ei, flag, E, nsblk, ngblk,
                                                      gcur, ebuf, x, pB1, h1s, NN);

    // 2) per-bucket CSR build (+ dinv, inline bucket-prefix)
    k_bucket_csr<<<NBUCK, 1024, 0, stream>>>(ebuf, gcur, rowst, dinv, csr, NN);

    // 3) layer-1 aggregate + bias + ReLU  (fp8 unscaled in -> bf16 out), 8 nodes/wave
    k_gather_relu<<<cdiv((long long)NN * 8, B), B, 0, stream>>>(rowst, csr, h1s, dinv, b1, agg1, NN);

    // 4) h2s = fp8( (agg1 @ W2) * dinv[row] )  via bf16 MFMA, bf16 A
    k_mfma_gemm<64, 40, 2, 3, true><<<cdiv(NN, 64), B, 0, stream>>>(agg1, pB2, dinv, h2s, NN);

    // 5) layer-2 aggregate + bias + log_softmax -> d_out (fp32), 8 nodes/wave
    k_gather_lsm<<<cdiv((long long)NN * 8, B), B, 0, stream>>>(rowst, csr, h2s, dinv, b2, out, NN);
}

// Round 17
// 179.568 us; speedup vs baseline: 1.2635x; 1.0026x over previous
//
#include <hip/hip_runtime.h>
#include <hip/hip_bf16.h>
#include <math.h>

static constexpr int NN    = 100000;            // N_NODES
static constexpr int BSH   = 9;                 // bucket covers 512 nodes
static constexpr int NBUCK = (NN + 511) >> 9;   // 196
static constexpr int EPB   = 8192;              // edges per scatter block
static constexpr int CAP   = 24576;             // per-bucket region capacity (avg 16.3k)

typedef __attribute__((ext_vector_type(8))) short short8;
typedef __attribute__((ext_vector_type(4))) float f32x4;
typedef __attribute__((ext_vector_type(2))) float f32x2;

// HW fp8 conversion (gfx950). Word-select args must be IMMEDIATE constants.
#if defined(__has_builtin)
#  if __has_builtin(__builtin_amdgcn_cvt_pk_f32_fp8) && __has_builtin(__builtin_amdgcn_cvt_pk_fp8_f32)
#    define USE_HW_FP8 1
#  endif
#endif
#ifndef USE_HW_FP8
#  define USE_HW_FP8 0
#endif

__device__ __forceinline__ short f2bf(float f) {
    __hip_bfloat16 h = __float2bfloat16(f);
    return __builtin_bit_cast(short, h);
}

// ---- software fp8 e4m3 (fallback only) ----
__device__ __forceinline__ float fp8_dec_sw(unsigned b) {
    unsigned u = ((b & 0x80u) << 24) | ((b & 0x7Fu) << 20);
    return __builtin_bit_cast(float, u) * 0x1p120f;
}
__device__ __forceinline__ unsigned fp8_enc_sw(float f) {
    unsigned u = __builtin_bit_cast(unsigned, f * 0x1p-120f);
    unsigned s = (u >> 24) & 0x80u;
    unsigned mag = u & 0x7FFFFFFFu;
    unsigned t = mag + 0x7FFFFu + ((mag >> 20) & 1u);
    unsigned r = t >> 20;
    if (r > 0x7Eu) r = 0x7Eu;
    return s | r;
}

template<bool HI>
__device__ __forceinline__ f32x2 dec2w(unsigned u) {
#if USE_HW_FP8
    return __builtin_amdgcn_cvt_pk_f32_fp8(u, HI);
#else
    unsigned w = HI ? (u >> 16) : u;
    f32x2 r;
    r.x = fp8_dec_sw(w & 0xFFu);
    r.y = fp8_dec_sw((w >> 8) & 0xFFu);
    return r;
#endif
}
__device__ __forceinline__ unsigned enc2(float a, float b) {
#if USE_HW_FP8
    return (unsigned)__builtin_amdgcn_cvt_pk_fp8_f32(a, b, 0, false);
#else
    return fp8_enc_sw(a) | (fp8_enc_sw(b) << 8);
#endif
}

// accumulate 8 fp8 (uint2) into f32x2 a[4]
__device__ __forceinline__ void acc8(f32x2* a, uint2 u) {
    a[0] += dec2w<false>(u.x);
    a[1] += dec2w<true>(u.x);
    a[2] += dec2w<false>(u.y);
    a[3] += dec2w<true>(u.y);
}
// fma-accumulate 8 fp8 scaled by ds
__device__ __forceinline__ void acc8s(f32x2* a, uint2 u, float ds) {
    f32x2 w = {ds, ds};
    a[0] = dec2w<false>(u.x) * w + a[0];
    a[1] = dec2w<true>(u.x)  * w + a[1];
    a[2] = dec2w<false>(u.y) * w + a[2];
    a[3] = dec2w<true>(u.y)  * w + a[3];
}

// ---- edge index load ----
__device__ __forceinline__ long long ldidx(const void* __restrict__ p, long long i, int is64) {
    if (is64) return ((const long long* __restrict__)p)[i];
    return (long long)((const int* __restrict__)p)[i];
}

// ---- weight pack (device helper) ----
template<int K, int NCOLS, int KT, int NT>
__device__ __forceinline__ void packB_dev(const float* __restrict__ W,
                                          short* __restrict__ P, int t) {
    if (t >= KT * NT * 64) return;
    int kt = t / (NT * 64);
    int nt = (t / 64) % NT;
    int l  = t & 63;
    int g  = l >> 4;
#pragma unroll
    for (int e = 0; e < 8; ++e) {
        int k   = kt * 32 + g * 8 + e;
        int col = nt * 16 + (l & 15);
        float v = (col < NCOLS) ? W[k * NCOLS + col] : 0.0f;
        P[t * 8 + e] = f2bf(v);
    }
}

// Fused init: block 0 = dtype-detect + gcur zero; blocks 1-8 = packB1; 9-10 = packB2.
__global__ void __launch_bounds__(256)
k_init(const unsigned int* __restrict__ e32, int* __restrict__ flag,
       int* __restrict__ gcur,
       const float* __restrict__ W1, short* __restrict__ pB1,
       const float* __restrict__ W2, short* __restrict__ pB2) {
    int blk = blockIdx.x, tid = threadIdx.x;
    if (blk == 0) {
        if (tid < NBUCK) gcur[tid] = 0;
        __shared__ int any_nz;
        if (tid == 0) any_nz = 0;
        __syncthreads();
        unsigned int nz = 0;
        for (int w = 1 + 2 * tid; w < 4096; w += 512)
            nz |= e32[w];
        if (nz) atomicOr(&any_nz, 1);
        __syncthreads();
        if (tid == 0) *flag = (any_nz == 0) ? 1 : 0;   // 1 => int64
    } else if (blk <= 8) {
        packB_dev<256, 64, 8, 4>(W1, pB1, (blk - 1) * 256 + tid);
    } else {
        packB_dev<64, 40, 2, 3>(W2, pB2, (blk - 9) * 256 + tid);
    }
}

// ---- FUSED scatter + gemm1 (checkerboard). Gemm half now stages FULL X rows
// through LDS with fully-coalesced 1KB bursts (64 rows/stage, 4 stages). ----
__global__ void __launch_bounds__(1024)
k_build_gemm1(const void* __restrict__ eidx, const int* __restrict__ flag, long long E,
              int nsblk, int ngblk, int* __restrict__ gcur, unsigned* __restrict__ ebuf,
              const float* __restrict__ X, const short* __restrict__ pB1,
              unsigned char* __restrict__ H, int n) {
    int bid = (int)blockIdx.x;
    int mn = nsblk < ngblk ? nsblk : ngblk;
    int role, idx;
    if (bid < 2 * mn) { role = bid & 1; idx = bid >> 1; }
    else {
        int rem = bid - 2 * mn;
        role = (nsblk > ngblk) ? 0 : 1;
        idx = mn + rem;
    }
    if (role == 0) {
        // ---- scatter half (register-cached edges, 8 per thread) ----
        __shared__ int h[NBUCK];
        for (int b = threadIdx.x; b < NBUCK; b += 1024) h[b] = 0;
        __syncthreads();
        int is64 = *flag;
        long long base = (long long)idx * EPB;
        long long end  = base + EPB < E ? base + EPB : E;
        unsigned sv[8], dv[8];
        bool ok[8];
#pragma unroll
        for (int k = 0; k < 8; ++k) {
            long long e = base + (long long)k * 1024 + threadIdx.x;
            ok[k] = (e < end);
            if (ok[k]) {
                sv[k] = (unsigned)ldidx(eidx, e, is64);
                dv[k] = (unsigned)ldidx(eidx, E + e, is64);
                atomicAdd(&h[dv[k] >> BSH], 1);
            }
        }
        __syncthreads();
        for (int b = threadIdx.x; b < NBUCK; b += 1024)
            h[b] = atomicAdd(&gcur[b], h[b]);
        __syncthreads();
#pragma unroll
        for (int k = 0; k < 8; ++k) {
            if (ok[k]) {
                int bk = dv[k] >> BSH;
                int pos = atomicAdd(&h[bk], 1);
                ebuf[(long long)bk * CAP + pos] = sv[k] | ((dv[k] & 511u) << 17);
            }
        }
    } else {
        // ---- gemm1 half: 256 rows/block, 4 stages of 64 rows through LDS ----
        __shared__ alignas(16) short sW[8 * 4 * 512];   // 32 KB packed W1
        __shared__ alignas(16) short sX[64 * 264];      // 33 KB bf16 rows (pad 8 shorts)
        short8* dst = (short8*)sW;
        const short8* src = (const short8*)pB1;
        int tid = threadIdx.x;
        for (int i = tid; i < 2048; i += 1024) dst[i] = src[i];

        int wave = tid >> 6, lane = tid & 63;
        int g = lane >> 4;
        int wig = wave & 3;    // wave-in-group (rows wig*16..wig*16+15 of the stage)
        int grp = wave >> 2;   // which stage this wave computes

        int lr = tid >> 4;             // staged row 0..63 this thread loads
        int c0 = (tid & 15) * 16;      // starting float col (64B chunks)

        for (int s = 0; s < 4; ++s) {
            // cooperative coalesced load: full 1KB rows -> bf16 LDS tile
            int grow = idx * 256 + s * 64 + lr;
            short* xd = &sX[lr * 264 + c0];
            if (grow < n) {
                const float* xr = X + (long long)grow * 256 + c0;
                float4 u0 = *(const float4*)(xr);
                float4 u1 = *(const float4*)(xr + 4);
                float4 u2 = *(const float4*)(xr + 8);
                float4 u3 = *(const float4*)(xr + 12);
                xd[0]  = f2bf(u0.x); xd[1]  = f2bf(u0.y); xd[2]  = f2bf(u0.z); xd[3]  = f2bf(u0.w);
                xd[4]  = f2bf(u1.x); xd[5]  = f2bf(u1.y); xd[6]  = f2bf(u1.z); xd[7]  = f2bf(u1.w);
                xd[8]  = f2bf(u2.x); xd[9]  = f2bf(u2.y); xd[10] = f2bf(u2.z); xd[11] = f2bf(u2.w);
                xd[12] = f2bf(u3.x); xd[13] = f2bf(u3.y); xd[14] = f2bf(u3.z); xd[15] = f2bf(u3.w);
            } else {
#pragma unroll
                for (int i = 0; i < 16; ++i) xd[i] = 0;
            }
            __syncthreads();
            if (grp == s) {
                f32x4 acc[4];
#pragma unroll
                for (int nt = 0; nt < 4; ++nt) acc[nt] = (f32x4){0.f, 0.f, 0.f, 0.f};
                const short* arow_p = &sX[(wig * 16 + (lane & 15)) * 264];
#pragma unroll
                for (int kt = 0; kt < 8; ++kt) {
                    short8 a = *(const short8*)(arow_p + kt * 32 + g * 8);
#pragma unroll
                    for (int nt = 0; nt < 4; ++nt) {
                        short8 bfr = dst[(kt * 4 + nt) * 64 + lane];
                        acc[nt] = __builtin_amdgcn_mfma_f32_16x16x32_bf16(a, bfr, acc[nt], 0, 0, 0);
                    }
                }
                // C/D layout: col = lane&15, row = (lane>>4)*4 + reg
                int c = lane & 15;
                int orow_base = idx * 256 + s * 64 + wig * 16 + g * 4;
#pragma unroll
                for (int r = 0; r < 4; ++r) {
                    int orow = orow_base + r;
                    if (orow < n) {
                        unsigned char* hp = H + (long long)orow * 64;
#pragma unroll
                        for (int p = 0; p < 4; p += 2) {
                            unsigned wrd = enc2(acc[p][r], acc[p + 1][r]);
                            hp[p * 16 + c]       = (unsigned char)(wrd & 0xFFu);
                            hp[(p + 1) * 16 + c] = (unsigned char)((wrd >> 8) & 0xFFu);
                        }
                    }
                }
            }
            __syncthreads();
        }
    }
}

// per bucket (512 nodes), 1024 threads: inline bucket-prefix, counts in LDS,
// wave-shuffle scan, emit rowst/dinv/csr.
__global__ void __launch_bounds__(1024)
k_bucket_csr(const unsigned* __restrict__ ebuf, const int* __restrict__ gcnt,
             int* __restrict__ rowst, float* __restrict__ dinv,
             int* __restrict__ csr, int n) {
    __shared__ int cnt[512];
    __shared__ int cursor[512];
    __shared__ int woff[8];
    __shared__ int bs_sh;
    int b = blockIdx.x;
    int t = threadIdx.x;
    int cb = gcnt[b];
    long long rbase = (long long)b * CAP;
    if (t == 0) bs_sh = 0;
    if (t < 512) cnt[t] = 0;
    __syncthreads();
    if (t < b) atomicAdd(&bs_sh, gcnt[t]);   // b <= 195 < 1024: full coverage
    for (int i = t; i < cb; i += 1024) {
        unsigned ed = ebuf[rbase + i];
        atomicAdd(&cnt[ed >> 17], 1);
    }
    __syncthreads();
    int bs = bs_sh;
    if (b == NBUCK - 1 && t == 0) rowst[n] = bs + cb;   // == E
    int v = 0, ps = 0;
    if (t < 512) {
        v = cnt[t];
        ps = v;
        int lane = t & 63;
#pragma unroll
        for (int off = 1; off < 64; off <<= 1) {
            int up = __shfl_up(ps, off);
            if (lane >= off) ps += up;
        }
        if (lane == 63) woff[t >> 6] = ps;   // wave inclusive total
    }
    __syncthreads();
    if (t == 0) {
        int run = 0;
#pragma unroll
        for (int i = 0; i < 8; ++i) { int x = woff[i]; woff[i] = run; run += x; }
    }
    __syncthreads();
    if (t < 512) {
        int incl  = ps + woff[t >> 6];
        int start = bs + incl - v;           // exclusive
        int gnode = (b << BSH) + t;
        if (gnode < n) {
            rowst[gnode] = start;
            dinv[gnode]  = rsqrtf((float)(v + 1));
        }
        cursor[t] = start;
    }
    __syncthreads();
    for (int i = t; i < cb; i += 1024) {
        unsigned ed = ebuf[rbase + i];
        int pos = atomicAdd(&cursor[ed >> 17], 1);
        csr[pos] = (int)(ed & 0x1FFFFu);
    }
}

// H[i,:] = fp8( (X[i,:K] @ W) * dinv[i] ), fp32 accumulate via bf16 MFMA. (gemm2)
template<int K, int NCOLS, int KT, int NT, bool ABF16>
__global__ void __launch_bounds__(256)
k_mfma_gemm(const void* __restrict__ Xv, const short* __restrict__ packedB,
            const float* __restrict__ dinv, unsigned char* __restrict__ H, int n) {
    __shared__ alignas(16) short sW[KT * NT * 512];
    short8* dst = (short8*)sW;
    const short8* src = (const short8*)packedB;
    constexpr int TOT8 = KT * NT * 64;
    for (int i = threadIdx.x; i < TOT8; i += 256) dst[i] = src[i];
    __syncthreads();

    int wave = threadIdx.x >> 6, lane = threadIdx.x & 63;
    int g = lane >> 4;
    int arow = blockIdx.x * 64 + wave * 16 + (lane & 15);

    f32x4 acc[NT];
#pragma unroll
    for (int nt = 0; nt < NT; ++nt) acc[nt] = (f32x4){0.f, 0.f, 0.f, 0.f};

#pragma unroll
    for (int kt = 0; kt < KT; ++kt) {
        short8 a;
        if (arow < n) {
            int k0 = kt * 32 + g * 8;
            if (ABF16) {
                const short* xr = (const short*)Xv + (long long)arow * K;
                a = *(const short8*)(xr + k0);
            } else {
                const float* xr = (const float*)Xv + (long long)arow * K;
                float4 u = *(const float4*)(xr + k0);
                float4 v = *(const float4*)(xr + k0 + 4);
                a[0] = f2bf(u.x); a[1] = f2bf(u.y); a[2] = f2bf(u.z); a[3] = f2bf(u.w);
                a[4] = f2bf(v.x); a[5] = f2bf(v.y); a[6] = f2bf(v.z); a[7] = f2bf(v.w);
            }
        } else {
            a = (short8){0, 0, 0, 0, 0, 0, 0, 0};
        }
#pragma unroll
        for (int nt = 0; nt < NT; ++nt) {
            short8 bfr = dst[(kt * NT + nt) * 64 + lane];
            acc[nt] = __builtin_amdgcn_mfma_f32_16x16x32_bf16(a, bfr, acc[nt], 0, 0, 0);
        }
    }

    int c = lane & 15;
    int orow_base = blockIdx.x * 64 + wave * 16 + g * 4;
#pragma unroll
    for (int r = 0; r < 4; ++r) {
        int orow = orow_base + r;
        if (orow < n) {
            float di = dinv[orow];
            float v[NT];
#pragma unroll
            for (int nt = 0; nt < NT; ++nt) v[nt] = acc[nt][r] * di;
            unsigned char* hp = H + (long long)orow * NCOLS;
#pragma unroll
            for (int p = 0; p < NT; p += 2) {
                unsigned wrd = enc2(v[p], (p + 1 < NT) ? v[p + 1] : 0.0f);
                int col0 = p * 16 + c;
                if (col0 < NCOLS) hp[col0] = (unsigned char)(wrd & 0xFFu);
                if (p + 1 < NT) {
                    int col1 = col0 + 16;
                    if (col1 < NCOLS) hp[col1] = (unsigned char)((wrd >> 8) & 0xFFu);
                }
            }
        }
    }
}

// Layer-1 aggregate (F=64 fp8, UNSCALED h1): ONE 8-LANE GROUP PER NODE.
// 4-deep unroll: 32 independent gathers in flight per wave.
__global__ void __launch_bounds__(256)
k_gather_relu(const int* __restrict__ rowst, const int* __restrict__ csr,
              const unsigned char* __restrict__ h1s, const float* __restrict__ dinv,
              const float* __restrict__ b, unsigned short* __restrict__ out, int n) {
    long long gid = (long long)blockIdx.x * blockDim.x + threadIdx.x;
    int node = (int)(gid >> 3);
    int fe   = (int)(gid & 7);
    if (node >= n) return;          // group-uniform
    int jb = rowst[node], je = rowst[node + 1];
    unsigned feoff = (unsigned)fe << 3;

    f32x2 a0[4], a1[4], a2[4], a3[4];
#pragma unroll
    for (int q = 0; q < 4; ++q) {
        a0[q] = (f32x2){0.f, 0.f}; a1[q] = (f32x2){0.f, 0.f};
        a2[q] = (f32x2){0.f, 0.f}; a3[q] = (f32x2){0.f, 0.f};
    }

    int j = jb;
    for (; j + 3 < je; j += 4) {
        int s0 = csr[j], s1 = csr[j + 1], s2 = csr[j + 2], s3 = csr[j + 3];
        float ds0 = dinv[s0], ds1 = dinv[s1], ds2 = dinv[s2], ds3 = dinv[s3];
        uint2 u0 = *(const uint2*)(h1s + (((unsigned)s0 << 6) + feoff));
        uint2 u1 = *(const uint2*)(h1s + (((unsigned)s1 << 6) + feoff));
        uint2 u2 = *(const uint2*)(h1s + (((unsigned)s2 << 6) + feoff));
        uint2 u3 = *(const uint2*)(h1s + (((unsigned)s3 << 6) + feoff));
        acc8s(a0, u0, ds0);
        acc8s(a1, u1, ds1);
        acc8s(a2, u2, ds2);
        acc8s(a3, u3, ds3);
    }
    for (; j < je; ++j) {
        int s0 = csr[j];
        float ds0 = dinv[s0];
        uint2 u0 = *(const uint2*)(h1s + (((unsigned)s0 << 6) + feoff));
        acc8s(a0, u0, ds0);
    }
#pragma unroll
    for (int q = 0; q < 4; ++q) a0[q] += (a1[q] + a2[q]) + a3[q];

    float dn = dinv[node];
    uint2 self = *(const uint2*)(h1s + (((unsigned)node << 6) + feoff));
    acc8s(a0, self, dn);
    unsigned short r[8];
#pragma unroll
    for (int q = 0; q < 4; ++q) {
        float v0 = fmaxf(a0[q].x * dn + b[8 * fe + 2 * q],     0.0f);
        float v1 = fmaxf(a0[q].y * dn + b[8 * fe + 2 * q + 1], 0.0f);
        r[2 * q]     = (unsigned short)f2bf(v0);
        r[2 * q + 1] = (unsigned short)f2bf(v1);
    }
    uint4 pk;
    pk.x = (unsigned)r[0] | ((unsigned)r[1] << 16);
    pk.y = (unsigned)r[2] | ((unsigned)r[3] << 16);
    pk.z = (unsigned)r[4] | ((unsigned)r[5] << 16);
    pk.w = (unsigned)r[6] | ((unsigned)r[7] << 16);
    ((uint4*)(out + (long long)node * 64))[fe] = pk;
}

// Layer-2 aggregate + bias + log_softmax (F=40 fp8 in, scaled; fp32 out).
// 4-deep unroll.
__global__ void __launch_bounds__(256)
k_gather_lsm(const int* __restrict__ rowst, const int* __restrict__ csr,
             const unsigned char* __restrict__ h2s, const float* __restrict__ dinv,
             const float* __restrict__ b, float* __restrict__ out, int n) {
    long long gid = (long long)blockIdx.x * blockDim.x + threadIdx.x;
    int node = (int)(gid >> 3);
    int fe   = (int)(gid & 7);
    if (node >= n) return;          // group-uniform
    bool act = (fe < 5);
    int jb = rowst[node], je = rowst[node + 1];
    unsigned feoff = (unsigned)fe << 3;

    f32x2 a0[4], a1[4], a2[4], a3[4];
#pragma unroll
    for (int q = 0; q < 4; ++q) {
        a0[q] = (f32x2){0.f, 0.f}; a1[q] = (f32x2){0.f, 0.f};
        a2[q] = (f32x2){0.f, 0.f}; a3[q] = (f32x2){0.f, 0.f};
    }

    int j = jb;
    for (; j + 3 < je; j += 4) {
        int s0 = csr[j], s1 = csr[j + 1], s2 = csr[j + 2], s3 = csr[j + 3];
        if (act) {
            uint2 u0 = *(const uint2*)(h2s + ((unsigned)s0 * 40u + feoff));
            uint2 u1 = *(const uint2*)(h2s + ((unsigned)s1 * 40u + feoff));
            uint2 u2 = *(const uint2*)(h2s + ((unsigned)s2 * 40u + feoff));
            uint2 u3 = *(const uint2*)(h2s + ((unsigned)s3 * 40u + feoff));
            acc8(a0, u0);
            acc8(a1, u1);
            acc8(a2, u2);
            acc8(a3, u3);
        }
    }
    for (; j < je; ++j) {
        int s0 = csr[j];
        if (act) {
            uint2 u0 = *(const uint2*)(h2s + ((unsigned)s0 * 40u + feoff));
            acc8(a0, u0);
        }
    }
#pragma unroll
    for (int q = 0; q < 4; ++q) a0[q] += (a1[q] + a2[q]) + a3[q];

    float va[8];
    float mloc = -INFINITY;
    if (act) {
        uint2 self = *(const uint2*)(h2s + ((unsigned)node * 40u + feoff));
        acc8(a0, self);
        float di = dinv[node];
#pragma unroll
        for (int q = 0; q < 4; ++q) {
            va[2 * q]     = a0[q].x * di + b[8 * fe + 2 * q];
            va[2 * q + 1] = a0[q].y * di + b[8 * fe + 2 * q + 1];
            mloc = fmaxf(mloc, fmaxf(va[2 * q], va[2 * q + 1]));
        }
    }
    float m = mloc;
    m = fmaxf(m, __shfl_xor(m, 1));
    m = fmaxf(m, __shfl_xor(m, 2));
    m = fmaxf(m, __shfl_xor(m, 4));
    float ex = 0.0f;
    if (act) {
#pragma unroll
        for (int k = 0; k < 8; ++k) ex += __expf(va[k] - m);
    }
    ex += __shfl_xor(ex, 1);
    ex += __shfl_xor(ex, 2);
    ex += __shfl_xor(ex, 4);
    float lse = __logf(ex);
    if (act) {
        float4 r0 = make_float4(va[0] - m - lse, va[1] - m - lse,
                                va[2] - m - lse, va[3] - m - lse);
        float4 r1 = make_float4(va[4] - m - lse, va[5] - m - lse,
                                va[6] - m - lse, va[7] - m - lse);
        *(float4*)(out + (long long)node * 40 + 8 * fe)     = r0;
        *(float4*)(out + (long long)node * 40 + 8 * fe + 4) = r1;
    }
}

extern "C" void kernel_launch(void* const* d_in, const int* in_sizes, int n_in,
                              void* d_out, int out_size, void* d_ws, size_t ws_size,
                              hipStream_t stream) {
    const float* x  = (const float*)d_in[0];
    const void*  ei = d_in[1];
    const float* W1 = (const float*)d_in[2];
    const float* b1 = (const float*)d_in[3];
    const float* W2 = (const float*)d_in[4];
    const float* b2 = (const float*)d_in[5];
    float* out = (float*)d_out;

    const long long E = (long long)in_sizes[1] / 2;   // 3,200,000
    const int nsblk = (int)((E + EPB - 1) / EPB);     // 391 scatter blocks
    const int ngblk = (NN + 255) / 256;               // 391 gemm1 blocks

    char* w = (char*)d_ws;
    auto alloc = [&](size_t bytes) -> void* {
        void* p = (void*)w;
        w += (bytes + 255) & ~(size_t)255;
        return p;
    };
    int*      flag    = (int*)     alloc(4);
    int*      gcur    = (int*)     alloc((size_t)NBUCK * 4);
    int*      rowst   = (int*)     alloc(((size_t)NN + 1) * 4);
    float*    dinv    = (float*)   alloc((size_t)NN * 4);
    short*    pB1     = (short*)   alloc((size_t)8 * 4 * 64 * 8 * 2);   // 32 KB
    short*    pB2     = (short*)   alloc((size_t)2 * 3 * 64 * 8 * 2);   // 6 KB
    int*      csr     = (int*)     alloc((size_t)E * 4);
    unsigned* ebuf    = (unsigned*)alloc((size_t)NBUCK * CAP * 4);      // 19.3 MB
    unsigned char* h1s = (unsigned char*)alloc((size_t)NN * 64);        // 6.4 MB (live with ebuf)
    unsigned short* agg1 = (unsigned short*)alloc((size_t)NN * 64 * 2);
    unsigned char* h2s = h1s;   // h1s dead after k_gather_relu

    const int B = 256;
    auto cdiv = [](long long a, long long b) { return (int)((a + b - 1) / b); };

    // 0) fused init: dtype detect + gcur zero + weight packing (one launch)
    k_init<<<11, B, 0, stream>>>((const unsigned int*)ei, flag, gcur, W1, pB1, W2, pB2);

    // 1) FUSED checkerboard: edge scatter + gemm1 (LDS-staged coalesced X)
    k_build_gemm1<<<nsblk + ngblk, 1024, 0, stream>>>(ei, flag, E, nsblk, ngblk,
                                                      gcur, ebuf, x, pB1, h1s, NN);

    // 2) per-bucket CSR build (+ dinv, inline bucket-prefix)
    k_bucket_csr<<<NBUCK, 1024, 0, stream>>>(ebuf, gcur, rowst, dinv, csr, NN);

    // 3) layer-1 aggregate + bias + ReLU  (fp8 unscaled in -> bf16 out), 8 nodes/wave
    k_gather_relu<<<cdiv((long long)NN * 8, B), B, 0, stream>>>(rowst, csr, h1s, dinv, b1, agg1, NN);

    // 4) h2s = fp8( (agg1 @ W2) * dinv[row] )  via bf16 MFMA, bf16 A
    k_mfma_gemm<64, 40, 2, 3, true><<<cdiv(NN, 64), B, 0, stream>>>(agg1, pB2, dinv, h2s, NN);

    // 5) layer-2 aggregate + bias + log_softmax -> d_out (fp32), 8 nodes/wave
    k_gather_lsm<<<cdiv((long long)NN * 8, B), B, 0, stream>>>(rowst, csr, h2s, dinv, b2, out, NN);
}